// Round 15
// baseline (623.172 us; speedup 1.0000x reference)
//
#include <hip/hip_runtime.h>
#include <math.h>
#include <float.h>

#define NPIX 16384
#define CC 192
#define BB 4
#define HHH 128
#define WWW 128
#define HID 510
#define HID2 1020
#define KKEEP 172
#define KSPLIT 16

typedef unsigned short ushort;
typedef unsigned int uint32;
using f32x4  = __attribute__((ext_vector_type(4))) float;
using bf16x8 = __attribute__((ext_vector_type(8))) short;

__device__ __forceinline__ float bf2f(ushort u) {
  union { float f; unsigned int i; } x; x.i = ((unsigned int)u) << 16; return x.f;
}
__device__ __forceinline__ ushort f2bf(float f) {
  union { float f; unsigned int i; } x; x.f = f;
  unsigned int r = (x.i + 0x7FFFu + ((x.i >> 16) & 1u)) >> 16;
  return (ushort)r;
}

struct __align__(16) us8 { ushort u[8]; };
struct __align__(8)  us4 { ushort u[4]; };

// ================= weight preconvert =================
__global__ __launch_bounds__(256) void k_wconv(
    const float* __restrict__ fiw, const float* __restrict__ fow,
    ushort* __restrict__ fiwb, ushort* __restrict__ fowb)
{
  const int idx = blockIdx.x * 256 + threadIdx.x;
  if (idx < 1024 * 192) {
    const int r = idx / 192, c = idx % 192;
    fiwb[idx] = (r < HID2) ? f2bf(fiw[r * 192 + c]) : (ushort)0;
  }
  const int i2 = idx - 1024 * 192;
  if (i2 >= 0 && i2 < 192 * 512) {
    const int r = i2 / 512, c = i2 % 512;
    fowb[i2] = (c < HID) ? f2bf(fow[r * HID + c]) : (ushort)0;
  }
}

// ================= transpose+split: fp32 [C][NPIX] -> hi/lo bf16 [NPIX][192] ==
__global__ __launch_bounds__(256) void k_tsplit(
    const float* __restrict__ X, ushort* __restrict__ Xh, ushort* __restrict__ Xl)
{
  __shared__ float ld[64][261];
  const int b = blockIdx.z;
  const int c0 = blockIdx.y * 64;
  const int px0 = blockIdx.x * 256;
  const int tid = threadIdx.x;
  #pragma unroll
  for (int i = 0; i < 16; ++i) {
    const int u = i * 256 + tid;
    const int r = u >> 6, p4 = (u & 63) * 4;
    const float4 v = *reinterpret_cast<const float4*>(
        X + ((size_t)b * CC + c0 + r) * NPIX + px0 + p4);
    ld[r][p4] = v.x; ld[r][p4 + 1] = v.y; ld[r][p4 + 2] = v.z; ld[r][p4 + 3] = v.w;
  }
  __syncthreads();
  const int c8 = (tid & 7) * 8;
  #pragma unroll
  for (int it = 0; it < 8; ++it) {
    const int pl = it * 32 + (tid >> 3);
    us8 hi, lo;
    #pragma unroll
    for (int j = 0; j < 8; ++j) {
      const float v = ld[c8 + j][pl];
      const ushort h = f2bf(v);
      hi.u[j] = h; lo.u[j] = f2bf(v - bf2f(h));
    }
    const size_t off = ((size_t)b * NPIX + px0 + pl) * CC + c0 + c8;
    *reinterpret_cast<us8*>(Xh + off) = hi;
    *reinterpret_cast<us8*>(Xl + off) = lo;
  }
}

// ================= resident NT 3-pass GEMM, 8-wave (q stage-1) ===============
__global__ __launch_bounds__(512) void k_nt3res(
    const float* __restrict__ W,
    const ushort* __restrict__ Bh, const ushort* __restrict__ Bl,
    const float* __restrict__ bias, float* __restrict__ C,
    long long sAb)
{
  __shared__ ushort As[2][64][200];
  __shared__ ushort Bs[2][128][200];
  const int b = blockIdx.z;
  const int n0 = blockIdx.x * 128;
  const int m0 = blockIdx.y * 64;
  const int tid = threadIdx.x;
  const int lane = tid & 63;
  const int wave = tid >> 6;
  const int wm = wave >> 2, wn = wave & 3;
  const float*  Wb  = W  + (size_t)b * sAb;
  const ushort* Bhb = Bh + (size_t)b * NPIX * CC;
  const ushort* Blb = Bl + (size_t)b * NPIX * CC;

  #pragma unroll
  for (int i = 0; i < 6; ++i) {
    const int u = i * 512 + tid;
    const int r = u / 48, c = (u % 48) * 4;
    const float4 v = *reinterpret_cast<const float4*>(Wb + (size_t)(m0 + r) * CC + c);
    const float e[4] = {v.x, v.y, v.z, v.w};
    us4 hi, lo;
    #pragma unroll
    for (int t = 0; t < 4; ++t) {
      const ushort h = f2bf(e[t]);
      hi.u[t] = h; lo.u[t] = f2bf(e[t] - bf2f(h));
    }
    *reinterpret_cast<us4*>(&As[0][r][c]) = hi;
    *reinterpret_cast<us4*>(&As[1][r][c]) = lo;
  }
  #pragma unroll
  for (int i = 0; i < 6; ++i) {
    const int u = i * 512 + tid;
    const int r = u / 24, c = (u % 24) * 8;
    *reinterpret_cast<us8*>(&Bs[0][r][c]) =
        *reinterpret_cast<const us8*>(Bhb + (size_t)(n0 + r) * CC + c);
    *reinterpret_cast<us8*>(&Bs[1][r][c]) =
        *reinterpret_cast<const us8*>(Blb + (size_t)(n0 + r) * CC + c);
  }
  __syncthreads();

  f32x4 acc[2][2];
  #pragma unroll
  for (int i = 0; i < 2; ++i)
    #pragma unroll
    for (int j = 0; j < 2; ++j) acc[i][j] = (f32x4){0.f, 0.f, 0.f, 0.f};

  #pragma unroll
  for (int kk = 0; kk < 6; ++kk) {
    bf16x8 af[2][2], bfg[2][2];
    #pragma unroll
    for (int mi = 0; mi < 2; ++mi)
      #pragma unroll
      for (int p = 0; p < 2; ++p)
        af[mi][p] = *reinterpret_cast<const bf16x8*>(
            &As[p][wm * 32 + mi * 16 + (lane & 15)][kk * 32 + (lane >> 4) * 8]);
    #pragma unroll
    for (int ni = 0; ni < 2; ++ni)
      #pragma unroll
      for (int p = 0; p < 2; ++p)
        bfg[ni][p] = *reinterpret_cast<const bf16x8*>(
            &Bs[p][wn * 32 + ni * 16 + (lane & 15)][kk * 32 + (lane >> 4) * 8]);
    #pragma unroll
    for (int mi = 0; mi < 2; ++mi)
      #pragma unroll
      for (int ni = 0; ni < 2; ++ni) {
        acc[mi][ni] = __builtin_amdgcn_mfma_f32_16x16x32_bf16(
            af[mi][0], bfg[ni][0], acc[mi][ni], 0, 0, 0);
        acc[mi][ni] = __builtin_amdgcn_mfma_f32_16x16x32_bf16(
            af[mi][0], bfg[ni][1], acc[mi][ni], 0, 0, 0);
        acc[mi][ni] = __builtin_amdgcn_mfma_f32_16x16x32_bf16(
            af[mi][1], bfg[ni][0], acc[mi][ni], 0, 0, 0);
      }
  }

  #pragma unroll
  for (int mi = 0; mi < 2; ++mi)
    #pragma unroll
    for (int r = 0; r < 4; ++r) {
      const int m = m0 + wm * 32 + mi * 16 + (lane >> 4) * 4 + r;
      const float bv = bias[m];
      #pragma unroll
      for (int ni = 0; ni < 2; ++ni) {
        const int n = n0 + wn * 32 + ni * 16 + (lane & 15);
        C[(size_t)b * CC * NPIX + (size_t)m * NPIX + n] = acc[mi][ni][r] + bv;
      }
    }
}

// ====== Fa GEMM: resident, B = fp32 v [c][px], transposed+split in staging ===
// C[m][px] = sum_c Mm[m][c]*v[c][px] + ob[m].  Same schedule as k_nt3res;
// B-staging uses the R5-verified fp32->hi/lo transpose pattern.
__global__ __launch_bounds__(512) void k_nt3fa(
    const float* __restrict__ W, const float* __restrict__ V,
    const float* __restrict__ bias, float* __restrict__ C)
{
  __shared__ ushort As[2][64][200];
  __shared__ ushort Bs[2][128][200];
  const int b = blockIdx.z;
  const int n0 = blockIdx.x * 128;
  const int m0 = blockIdx.y * 64;
  const int tid = threadIdx.x;
  const int lane = tid & 63;
  const int wave = tid >> 6;
  const int wm = wave >> 2, wn = wave & 3;
  const float* Wb = W + (size_t)b * CC * CC;
  const float* Vb = V + (size_t)b * CC * NPIX;

  #pragma unroll
  for (int i = 0; i < 6; ++i) {
    const int u = i * 512 + tid;
    const int r = u / 48, c = (u % 48) * 4;
    const float4 v = *reinterpret_cast<const float4*>(Wb + (size_t)(m0 + r) * CC + c);
    const float e[4] = {v.x, v.y, v.z, v.w};
    us4 hi, lo;
    #pragma unroll
    for (int t = 0; t < 4; ++t) {
      const ushort h = f2bf(e[t]);
      hi.u[t] = h; lo.u[t] = f2bf(e[t] - bf2f(h));
    }
    *reinterpret_cast<us4*>(&As[0][r][c]) = hi;
    *reinterpret_cast<us4*>(&As[1][r][c]) = lo;
  }
  // B: 6 chunks of [32c][128px], transpose+split into Bs[p][px][c]
  {
    const int krp = tid >> 5;          // 0..15 -> c-rows 2krp, 2krp+1
    const int n4 = (tid & 31) * 4;     // 0..124
    #pragma unroll
    for (int kk0 = 0; kk0 < CC; kk0 += 32) {
      const float4 f0 = *reinterpret_cast<const float4*>(
          Vb + (size_t)(kk0 + 2 * krp) * NPIX + n0 + n4);
      const float4 f1 = *reinterpret_cast<const float4*>(
          Vb + (size_t)(kk0 + 2 * krp + 1) * NPIX + n0 + n4);
      const float e0[4] = {f0.x, f0.y, f0.z, f0.w};
      const float e1[4] = {f1.x, f1.y, f1.z, f1.w};
      #pragma unroll
      for (int j = 0; j < 4; ++j) {
        const ushort h0 = f2bf(e0[j]), h1 = f2bf(e1[j]);
        const ushort l0 = f2bf(e0[j] - bf2f(h0)), l1 = f2bf(e1[j] - bf2f(h1));
        *reinterpret_cast<uint32*>(&Bs[0][n4 + j][kk0 + 2 * krp]) =
            (uint32)h0 | ((uint32)h1 << 16);
        *reinterpret_cast<uint32*>(&Bs[1][n4 + j][kk0 + 2 * krp]) =
            (uint32)l0 | ((uint32)l1 << 16);
      }
    }
  }
  __syncthreads();

  f32x4 acc[2][2];
  #pragma unroll
  for (int i = 0; i < 2; ++i)
    #pragma unroll
    for (int j = 0; j < 2; ++j) acc[i][j] = (f32x4){0.f, 0.f, 0.f, 0.f};

  #pragma unroll
  for (int kk = 0; kk < 6; ++kk) {
    bf16x8 af[2][2], bfg[2][2];
    #pragma unroll
    for (int mi = 0; mi < 2; ++mi)
      #pragma unroll
      for (int p = 0; p < 2; ++p)
        af[mi][p] = *reinterpret_cast<const bf16x8*>(
            &As[p][wm * 32 + mi * 16 + (lane & 15)][kk * 32 + (lane >> 4) * 8]);
    #pragma unroll
    for (int ni = 0; ni < 2; ++ni)
      #pragma unroll
      for (int p = 0; p < 2; ++p)
        bfg[ni][p] = *reinterpret_cast<const bf16x8*>(
            &Bs[p][wn * 32 + ni * 16 + (lane & 15)][kk * 32 + (lane >> 4) * 8]);
    #pragma unroll
    for (int mi = 0; mi < 2; ++mi)
      #pragma unroll
      for (int ni = 0; ni < 2; ++ni) {
        acc[mi][ni] = __builtin_amdgcn_mfma_f32_16x16x32_bf16(
            af[mi][0], bfg[ni][0], acc[mi][ni], 0, 0, 0);
        acc[mi][ni] = __builtin_amdgcn_mfma_f32_16x16x32_bf16(
            af[mi][0], bfg[ni][1], acc[mi][ni], 0, 0, 0);
        acc[mi][ni] = __builtin_amdgcn_mfma_f32_16x16x32_bf16(
            af[mi][1], bfg[ni][0], acc[mi][ni], 0, 0, 0);
      }
  }

  #pragma unroll
  for (int mi = 0; mi < 2; ++mi)
    #pragma unroll
    for (int r = 0; r < 4; ++r) {
      const int m = m0 + wm * 32 + mi * 16 + (lane >> 4) * 4 + r;
      const float bv = bias[m];
      #pragma unroll
      for (int ni = 0; ni < 2; ++ni) {
        const int n = n0 + wn * 32 + ni * 16 + (lane & 15);
        C[(size_t)b * CC * NPIX + (size_t)m * NPIX + n] = acc[mi][ni][r] + bv;
      }
    }
}

// ================= merged k+v stage-1, 8-wave — R11-verified =================
__global__ __launch_bounds__(512) void k_nt3res2(
    const float* __restrict__ W1, const float* __restrict__ W2,
    const ushort* __restrict__ Bh, const ushort* __restrict__ Bl,
    const float* __restrict__ b1, const float* __restrict__ b2,
    float* __restrict__ C1, float* __restrict__ C2)
{
  __shared__ ushort As[2][64][200];
  __shared__ ushort Bs[2][128][200];
  const int b = blockIdx.z;
  const int n0 = blockIdx.x * 128;
  const bool sel = blockIdx.y >= 3;
  const int m0 = (sel ? (blockIdx.y - 3) : blockIdx.y) * 64;
  const float* W = sel ? W2 : W1;
  const float* bias = sel ? b2 : b1;
  float* C = sel ? C2 : C1;
  const int tid = threadIdx.x;
  const int lane = tid & 63;
  const int wave = tid >> 6;
  const int wm = wave >> 2, wn = wave & 3;
  const ushort* Bhb = Bh + (size_t)b * NPIX * CC;
  const ushort* Blb = Bl + (size_t)b * NPIX * CC;

  #pragma unroll
  for (int i = 0; i < 6; ++i) {
    const int u = i * 512 + tid;
    const int r = u / 48, c = (u % 48) * 4;
    const float4 v = *reinterpret_cast<const float4*>(W + (size_t)(m0 + r) * CC + c);
    const float e[4] = {v.x, v.y, v.z, v.w};
    us4 hi, lo;
    #pragma unroll
    for (int t = 0; t < 4; ++t) {
      const ushort h = f2bf(e[t]);
      hi.u[t] = h; lo.u[t] = f2bf(e[t] - bf2f(h));
    }
    *reinterpret_cast<us4*>(&As[0][r][c]) = hi;
    *reinterpret_cast<us4*>(&As[1][r][c]) = lo;
  }
  #pragma unroll
  for (int i = 0; i < 6; ++i) {
    const int u = i * 512 + tid;
    const int r = u / 24, c = (u % 24) * 8;
    *reinterpret_cast<us8*>(&Bs[0][r][c]) =
        *reinterpret_cast<const us8*>(Bhb + (size_t)(n0 + r) * CC + c);
    *reinterpret_cast<us8*>(&Bs[1][r][c]) =
        *reinterpret_cast<const us8*>(Blb + (size_t)(n0 + r) * CC + c);
  }
  __syncthreads();

  f32x4 acc[2][2];
  #pragma unroll
  for (int i = 0; i < 2; ++i)
    #pragma unroll
    for (int j = 0; j < 2; ++j) acc[i][j] = (f32x4){0.f, 0.f, 0.f, 0.f};

  #pragma unroll
  for (int kk = 0; kk < 6; ++kk) {
    bf16x8 af[2][2], bfg[2][2];
    #pragma unroll
    for (int mi = 0; mi < 2; ++mi)
      #pragma unroll
      for (int p = 0; p < 2; ++p)
        af[mi][p] = *reinterpret_cast<const bf16x8*>(
            &As[p][wm * 32 + mi * 16 + (lane & 15)][kk * 32 + (lane >> 4) * 8]);
    #pragma unroll
    for (int ni = 0; ni < 2; ++ni)
      #pragma unroll
      for (int p = 0; p < 2; ++p)
        bfg[ni][p] = *reinterpret_cast<const bf16x8*>(
            &Bs[p][wn * 32 + ni * 16 + (lane & 15)][kk * 32 + (lane >> 4) * 8]);
    #pragma unroll
    for (int mi = 0; mi < 2; ++mi)
      #pragma unroll
      for (int ni = 0; ni < 2; ++ni) {
        acc[mi][ni] = __builtin_amdgcn_mfma_f32_16x16x32_bf16(
            af[mi][0], bfg[ni][0], acc[mi][ni], 0, 0, 0);
        acc[mi][ni] = __builtin_amdgcn_mfma_f32_16x16x32_bf16(
            af[mi][0], bfg[ni][1], acc[mi][ni], 0, 0, 0);
        acc[mi][ni] = __builtin_amdgcn_mfma_f32_16x16x32_bf16(
            af[mi][1], bfg[ni][0], acc[mi][ni], 0, 0, 0);
      }
  }

  #pragma unroll
  for (int mi = 0; mi < 2; ++mi)
    #pragma unroll
    for (int r = 0; r < 4; ++r) {
      const int m = m0 + wm * 32 + mi * 16 + (lane >> 4) * 4 + r;
      const float bv = bias[m];
      #pragma unroll
      for (int ni = 0; ni < 2; ++ni) {
        const int n = n0 + wn * 32 + ni * 16 + (lane & 15);
        C[(size_t)b * CC * NPIX + (size_t)m * NPIX + n] = acc[mi][ni][r] + bv;
      }
    }
}

// ================= fi GEMM v2: 64m x 128n, 76.8 KB LDS — R11-verified ========
__global__ __launch_bounds__(256) void k_fi(
    const ushort* __restrict__ Aw, const ushort* __restrict__ Bt,
    const float* __restrict__ bias, ushort* __restrict__ H)
{
  __shared__ ushort lds[64 * 200 + 128 * 200];
  ushort (*As)[200] = reinterpret_cast<ushort(*)[200]>(lds);
  ushort (*Bs)[200] = reinterpret_cast<ushort(*)[200]>(lds + 64 * 200);
  ushort (*Cs)[132] = reinterpret_cast<ushort(*)[132]>(lds);
  const int z = blockIdx.z;
  const int n0 = blockIdx.x * 128;
  const int m0 = blockIdx.y * 64;
  const int tid = threadIdx.x;
  const int lane = tid & 63;
  const int wave = tid >> 6;
  const int wm = wave >> 1, wn = wave & 1;
  const ushort* Bb = Bt + (size_t)z * NPIX * CC;
  ushort* Hb = H + (size_t)z * 1024 * NPIX;

  #pragma unroll
  for (int i = 0; i < 6; ++i) {
    const int u = i * 256 + tid;
    const int r = u / 24, c = (u % 24) * 8;
    *reinterpret_cast<us8*>(&As[r][c]) =
        *reinterpret_cast<const us8*>(Aw + (size_t)(m0 + r) * CC + c);
  }
  #pragma unroll
  for (int i = 0; i < 12; ++i) {
    const int u = i * 256 + tid;
    const int r = u / 24, c = (u % 24) * 8;
    *reinterpret_cast<us8*>(&Bs[r][c]) =
        *reinterpret_cast<const us8*>(Bb + (size_t)(n0 + r) * CC + c);
  }
  __syncthreads();

  f32x4 acc[2][4];
  #pragma unroll
  for (int i = 0; i < 2; ++i)
    #pragma unroll
    for (int j = 0; j < 4; ++j) acc[i][j] = (f32x4){0.f, 0.f, 0.f, 0.f};

  #pragma unroll
  for (int kk = 0; kk < 6; ++kk) {
    bf16x8 af[2], bfg[4];
    #pragma unroll
    for (int mi = 0; mi < 2; ++mi)
      af[mi] = *reinterpret_cast<const bf16x8*>(
          &As[wm * 32 + mi * 16 + (lane & 15)][kk * 32 + (lane >> 4) * 8]);
    #pragma unroll
    for (int ni = 0; ni < 4; ++ni)
      bfg[ni] = *reinterpret_cast<const bf16x8*>(
          &Bs[wn * 64 + ni * 16 + (lane & 15)][kk * 32 + (lane >> 4) * 8]);
    #pragma unroll
    for (int mi = 0; mi < 2; ++mi)
      #pragma unroll
      for (int ni = 0; ni < 4; ++ni)
        acc[mi][ni] = __builtin_amdgcn_mfma_f32_16x16x32_bf16(
            af[mi], bfg[ni], acc[mi][ni], 0, 0, 0);
  }

  __syncthreads();
  #pragma unroll
  for (int mi = 0; mi < 2; ++mi)
    #pragma unroll
    for (int rr = 0; rr < 4; ++rr) {
      const int rloc = wm * 32 + mi * 16 + (lane >> 4) * 4 + rr;
      const int m = m0 + rloc;
      const float bv = (m < HID2) ? bias[m] : 0.f;
      #pragma unroll
      for (int ni = 0; ni < 4; ++ni) {
        const int cc = wn * 64 + ni * 16 + (lane & 15);
        Cs[rloc][cc] = f2bf(acc[mi][ni][rr] + bv);
      }
    }
  __syncthreads();
  #pragma unroll
  for (int it = 0; it < 4; ++it) {
    const int r = it * 16 + (tid >> 4);
    const int c8 = (tid & 15) * 8;
    *reinterpret_cast<us8*>(Hb + (size_t)(m0 + r) * NPIX + n0 + c8) =
        *reinterpret_cast<const us8*>(&Cs[r][c8]);
  }
}

// ================= fo GEMM: A resident, B double-buffered — R11-verified =====
__global__ __launch_bounds__(256) void k_fo(
    const ushort* __restrict__ Aw, const ushort* __restrict__ Bt,
    const float* __restrict__ bias, const float* __restrict__ res,
    float* __restrict__ C)
{
  __shared__ ushort As[64][520];
  __shared__ ushort Bs[2][128][136];
  const int z = blockIdx.z;
  const int n0 = blockIdx.x * 128;
  const int m0 = blockIdx.y * 64;
  const int tid = threadIdx.x;
  const int lane = tid & 63;
  const int wave = tid >> 6;
  const int wm = wave >> 1, wn = wave & 1;
  const ushort* Bb = Bt + (size_t)z * NPIX * 512;
  const float* resb = res + (size_t)z * CC * NPIX;
  float* Cb = C + (size_t)z * CC * NPIX;

  #pragma unroll
  for (int i = 0; i < 16; ++i) {
    const int u = i * 256 + tid;
    const int r = u >> 6, c = (u & 63) * 8;
    *reinterpret_cast<us8*>(&As[r][c]) =
        *reinterpret_cast<const us8*>(Aw + (size_t)(m0 + r) * 512 + c);
  }
  #pragma unroll
  for (int i = 0; i < 8; ++i) {
    const int u = i * 256 + tid;
    const int r = u >> 4, c = (u & 15) * 8;
    *reinterpret_cast<us8*>(&Bs[0][r][c]) =
        *reinterpret_cast<const us8*>(Bb + (size_t)(n0 + r) * 512 + c);
  }
  __syncthreads();

  f32x4 acc[2][4];
  #pragma unroll
  for (int i = 0; i < 2; ++i)
    #pragma unroll
    for (int j = 0; j < 4; ++j) acc[i][j] = (f32x4){0.f, 0.f, 0.f, 0.f};

  for (int t = 0; t < 4; ++t) {
    us8 rg[8];
    if (t < 3) {
      #pragma unroll
      for (int i = 0; i < 8; ++i) {
        const int u = i * 256 + tid;
        const int r = u >> 4, c = (u & 15) * 8;
        rg[i] = *reinterpret_cast<const us8*>(
            Bb + (size_t)(n0 + r) * 512 + (t + 1) * 128 + c);
      }
    }
    const int cur = t & 1;
    #pragma unroll
    for (int ks = 0; ks < 4; ++ks) {
      bf16x8 af[2], bfg[4];
      #pragma unroll
      for (int mi = 0; mi < 2; ++mi)
        af[mi] = *reinterpret_cast<const bf16x8*>(
            &As[wm * 32 + mi * 16 + (lane & 15)][t * 128 + ks * 32 + (lane >> 4) * 8]);
      #pragma unroll
      for (int ni = 0; ni < 4; ++ni)
        bfg[ni] = *reinterpret_cast<const bf16x8*>(
            &Bs[cur][wn * 64 + ni * 16 + (lane & 15)][ks * 32 + (lane >> 4) * 8]);
      #pragma unroll
      for (int mi = 0; mi < 2; ++mi)
        #pragma unroll
        for (int ni = 0; ni < 4; ++ni)
          acc[mi][ni] = __builtin_amdgcn_mfma_f32_16x16x32_bf16(
              af[mi], bfg[ni], acc[mi][ni], 0, 0, 0);
    }
    if (t < 3) {
      #pragma unroll
      for (int i = 0; i < 8; ++i) {
        const int u = i * 256 + tid;
        const int r = u >> 4, c = (u & 15) * 8;
        *reinterpret_cast<us8*>(&Bs[cur ^ 1][r][c]) = rg[i];
      }
    }
    __syncthreads();
  }

  #pragma unroll
  for (int mi = 0; mi < 2; ++mi)
    #pragma unroll
    for (int r = 0; r < 4; ++r) {
      const int m = m0 + wm * 32 + mi * 16 + (lane >> 4) * 4 + r;
      const float bv = bias[m];
      #pragma unroll
      for (int ni = 0; ni < 4; ++ni) {
        const int n = n0 + wn * 64 + ni * 16 + (lane & 15);
        Cb[(size_t)m * NPIX + n] = acc[mi][ni][r] + bv + resb[(size_t)m * NPIX + n];
      }
    }
}

// ================= attn logits: MFMA 3-pass split-K — verified ===============
__global__ __launch_bounds__(256) void k_attn_mfma(
    const ushort* __restrict__ qh, const ushort* __restrict__ ql,
    const ushort* __restrict__ kh, const ushort* __restrict__ kl,
    float* __restrict__ part)
{
  __shared__ ushort As[2][64][40];
  __shared__ ushort Bs[2][64][40];
  const int b = blockIdx.z;
  const int tr = blockIdx.x / 3, tc = blockIdx.x % 3;
  const int r0 = tr * 64, c0 = tc * 64;
  const int k0 = blockIdx.y * (NPIX / KSPLIT);
  const int tid = threadIdx.x;
  const int lane = tid & 63;
  const int wave = tid >> 6;
  const int wm = wave >> 1, wn = wave & 1;

  f32x4 acc[2][2];
  #pragma unroll
  for (int i = 0; i < 2; ++i)
    #pragma unroll
    for (int j = 0; j < 2; ++j) acc[i][j] = (f32x4){0.f, 0.f, 0.f, 0.f};

  const int ar = tid >> 2, ak = (tid & 3) * 8;

  for (int kc = 0; kc < NPIX / KSPLIT; kc += 32) {
    const size_t qo = (size_t)(b * CC + r0 + ar) * NPIX + k0 + kc + ak;
    const size_t ko = (size_t)(b * CC + c0 + ar) * NPIX + k0 + kc + ak;
    *reinterpret_cast<us8*>(&As[0][ar][ak]) = *reinterpret_cast<const us8*>(qh + qo);
    *reinterpret_cast<us8*>(&As[1][ar][ak]) = *reinterpret_cast<const us8*>(ql + qo);
    *reinterpret_cast<us8*>(&Bs[0][ar][ak]) = *reinterpret_cast<const us8*>(kh + ko);
    *reinterpret_cast<us8*>(&Bs[1][ar][ak]) = *reinterpret_cast<const us8*>(kl + ko);
    __syncthreads();
    bf16x8 af[2][2], bfr[2][2];
    #pragma unroll
    for (int mi = 0; mi < 2; ++mi)
      #pragma unroll
      for (int p = 0; p < 2; ++p)
        af[mi][p] = *reinterpret_cast<const bf16x8*>(
            &As[p][wm * 32 + mi * 16 + (lane & 15)][(lane >> 4) * 8]);
    #pragma unroll
    for (int ni = 0; ni < 2; ++ni)
      #pragma unroll
      for (int p = 0; p < 2; ++p)
        bfr[ni][p] = *reinterpret_cast<const bf16x8*>(
            &Bs[p][wn * 32 + ni * 16 + (lane & 15)][(lane >> 4) * 8]);
    #pragma unroll
    for (int mi = 0; mi < 2; ++mi)
      #pragma unroll
      for (int ni = 0; ni < 2; ++ni) {
        acc[mi][ni] = __builtin_amdgcn_mfma_f32_16x16x32_bf16(
            af[mi][0], bfr[ni][0], acc[mi][ni], 0, 0, 0);
        acc[mi][ni] = __builtin_amdgcn_mfma_f32_16x16x32_bf16(
            af[mi][0], bfr[ni][1], acc[mi][ni], 0, 0, 0);
        acc[mi][ni] = __builtin_amdgcn_mfma_f32_16x16x32_bf16(
            af[mi][1], bfr[ni][0], acc[mi][ni], 0, 0, 0);
      }
    __syncthreads();
  }

  float* pp = part + (size_t)(blockIdx.y * BB + b) * CC * CC;
  #pragma unroll
  for (int mi = 0; mi < 2; ++mi)
    #pragma unroll
    for (int r = 0; r < 4; ++r) {
      const int row = r0 + wm * 32 + mi * 16 + (lane >> 4) * 4 + r;
      #pragma unroll
      for (int ni = 0; ni < 2; ++ni) {
        const int col = c0 + wn * 32 + ni * 16 + (lane & 15);
        pp[(size_t)row * CC + col] = acc[mi][ni][r];
      }
    }
}

// ================= depthwise 3x3 helper =================
__device__ __forceinline__ void dw4(const float* __restrict__ Xc,
                                    const float* __restrict__ wt, float bv,
                                    int h, int w, float out[4])
{
  float a0, a1, a2, a3;
  a0 = a1 = a2 = a3 = bv;
  #pragma unroll
  for (int dy = 0; dy < 3; ++dy) {
    const int hh = h + dy - 1;
    if (hh < 0 || hh >= HHH) continue;
    const float* row = Xc + hh * WWW + w;
    const float xm = (w > 0) ? row[-1] : 0.f;
    const float4 xc = *reinterpret_cast<const float4*>(row);
    const float xp = (w < WWW - 4) ? row[4] : 0.f;
    const float w0 = wt[dy * 3 + 0], w1 = wt[dy * 3 + 1], w2 = wt[dy * 3 + 2];
    a0 += w0 * xm   + w1 * xc.x + w2 * xc.y;
    a1 += w0 * xc.x + w1 * xc.y + w2 * xc.z;
    a2 += w0 * xc.y + w1 * xc.z + w2 * xc.w;
    a3 += w0 * xc.z + w1 * xc.w + w2 * xp;
  }
  out[0] = a0; out[1] = a1; out[2] = a2; out[3] = a3;
}

// plain dw3x3 (v path) — R11-verified
__global__ __launch_bounds__(256) void k_dw3x3(
    const float* __restrict__ X, const float* __restrict__ W9,
    const float* __restrict__ bias, float* __restrict__ Y)
{
  const int b = blockIdx.z, c = blockIdx.y;
  const int p = blockIdx.x * 1024 + threadIdx.x * 4;
  const int h = p >> 7, w = p & 127;
  float o[4];
  dw4(X + (size_t)(b * CC + c) * NPIX, W9 + c * 9, bias[c], h, w, o);
  *reinterpret_cast<float4*>(Y + (size_t)(b * CC + c) * NPIX + p) =
      make_float4(o[0], o[1], o[2], o[3]);
}

// dw3x3 + hi/lo split planes [c][px] + row-norm partials (fused) — verified
__global__ __launch_bounds__(256) void k_dw3x3_split(
    const float* __restrict__ X, const float* __restrict__ W9,
    const float* __restrict__ bias, ushort* __restrict__ Yh,
    ushort* __restrict__ Yl, float* __restrict__ partial)
{
  const int b = blockIdx.z, c = blockIdx.y;
  const int p = blockIdx.x * 1024 + threadIdx.x * 4;
  const int h = p >> 7, w = p & 127;
  float o[4];
  dw4(X + (size_t)(b * CC + c) * NPIX, W9 + c * 9, bias[c], h, w, o);
  us4 hi, lo;
  #pragma unroll
  for (int t = 0; t < 4; ++t) {
    const ushort hv = f2bf(o[t]);
    hi.u[t] = hv;
    lo.u[t] = f2bf(o[t] - bf2f(hv));
  }
  const size_t off = (size_t)(b * CC + c) * NPIX + p;
  *reinterpret_cast<us4*>(Yh + off) = hi;
  *reinterpret_cast<us4*>(Yl + off) = lo;
  __shared__ float sm[256];
  sm[threadIdx.x] = o[0]*o[0] + o[1]*o[1] + o[2]*o[2] + o[3]*o[3];
  __syncthreads();
  for (int st = 128; st > 0; st >>= 1) {
    if (threadIdx.x < st) sm[threadIdx.x] += sm[threadIdx.x + st];
    __syncthreads();
  }
  if (threadIdx.x == 0)
    partial[(size_t)(b * CC + c) * 16 + blockIdx.x] = sm[0];
}

// finalize reciprocal norms from partials (fixed order -> deterministic)
__global__ __launch_bounds__(256) void k_rnfin(
    const float* __restrict__ pq, const float* __restrict__ pk,
    float* __restrict__ rq, float* __restrict__ rk)
{
  const int row = blockIdx.x * 256 + threadIdx.x;
  if (row >= BB * CC) return;
  const float* p = blockIdx.y ? pk : pq;
  float s = 0.f;
  for (int i = 0; i < 16; ++i) s += p[(size_t)row * 16 + i];
  (blockIdx.y ? rk : rq)[row] = 1.f / fmaxf(sqrtf(s), 1e-12f);
}

// ================= softmax + topk mask =================
__global__ __launch_bounds__(192) void k_softmax_topk(
    const float* __restrict__ part, const float* __restrict__ rq,
    const float* __restrict__ rk, const float* __restrict__ temp,
    float* __restrict__ attnm)
{
  const int c = blockIdx.x, b = blockIdx.y, d = threadIdx.x;
  float s = 0.f;
  for (int ksp = 0; ksp < KSPLIT; ++ksp)
    s += part[(size_t)(ksp * BB + b) * CC * CC + c * CC + d];
  const float logit = s * rq[b * CC + c] * rk[b * CC + d] * temp[0];
  __shared__ float sa[CC], sb[CC];
  sa[d] = logit; __syncthreads();
  float mx = -FLT_MAX;
  for (int j = 0; j < CC; ++j) mx = fmaxf(mx, sa[j]);
  const float e = expf(logit - mx);
  sb[d] = e; __syncthreads();
  float sum = 0.f;
  for (int j = 0; j < CC; ++j) sum += sb[j];
  const float pv = e / sum;
  __syncthreads();
  sa[d] = pv; __syncthreads();
  int greater = 0;
  for (int j = 0; j < CC; ++j) greater += (sa[j] > pv) ? 1 : 0;
  const float cand = (greater < KKEEP) ? pv : FLT_MAX;
  sb[d] = cand; __syncthreads();
  float thr = FLT_MAX;
  for (int j = 0; j < CC; ++j) thr = fminf(thr, sb[j]);
  attnm[(size_t)(b * CC + c) * CC + d] = (pv >= thr) ? pv : 0.f;
}

// ================= M[b] = ow @ attnm[b] =================
__global__ __launch_bounds__(192) void k_mix(
    const float* __restrict__ ow, const float* __restrict__ attnm,
    float* __restrict__ M)
{
  const int c = blockIdx.x, b = blockIdx.y, d = threadIdx.x;
  float acc = 0.f;
  for (int e = 0; e < CC; ++e)
    acc += ow[c * CC + e] * attnm[(size_t)(b * CC + e) * CC + d];
  M[(size_t)(b * CC + c) * CC + d] = acc;
}

// ================= LayerNorm -> transposed bf16 [px][192] =================
__global__ __launch_bounds__(256) void k_ln_t(
    const float* __restrict__ X, const float* __restrict__ lw,
    const float* __restrict__ lb, ushort* __restrict__ Y)
{
  const int b = blockIdx.y;
  const int n = blockIdx.x * 256 + threadIdx.x;
  const float* Xb = X + (size_t)b * CC * NPIX + n;
  float s = 0.f, s2 = 0.f;
  for (int ci = 0; ci < CC; ++ci) {
    const float v = Xb[(size_t)ci * NPIX];
    s += v; s2 += v * v;
  }
  const float mu = s * (1.f / CC);
  const float var = fmaxf(s2 * (1.f / CC) - mu * mu, 0.f);
  const float rstd = rsqrtf(var + 1e-5f);
  ushort* Yb = Y + ((size_t)b * NPIX + n) * CC;
  for (int c8 = 0; c8 < CC / 8; ++c8) {
    bf16x8 sv;
    #pragma unroll
    for (int t = 0; t < 8; ++t) {
      const int c = c8 * 8 + t;
      const float v = Xb[(size_t)c * NPIX];
      sv[t] = (short)f2bf((v - mu) * rstd * lw[c] + lb[c]);
    }
    *reinterpret_cast<bf16x8*>(Yb + c8 * 8) = sv;
  }
}

// ================= fused depthwise 3x3 + GLU v3 — verified R8 ================
__device__ __forceinline__ float gelu_exact(float x) {
  return 0.5f * x * (1.f + erff(x * 0.70710678118654752f));
}

__global__ __launch_bounds__(256) void k_dwglu3(
    const ushort* __restrict__ Hp, const float* __restrict__ fdw,
    const float* __restrict__ fdb, ushort* __restrict__ gt)
{
  __shared__ ushort hs[16][4][128];
  __shared__ uint32 gsd[8 * 129];
  const int z = blockIdx.z;
  const int c0 = blockIdx.x * 8;
  const int h0 = blockIdx.y * 2;
  const int tid = threadIdx.x;
  const int npairs = min(8, HID - c0);
  const ushort* Hb = Hp + (size_t)z * 1024 * NPIX;

  #pragma unroll
  for (int i = 0; i < 4; ++i) {
    const int u = i * 256 + tid;
    const int ch = u >> 6;
    const int row = (u >> 4) & 3;
    const int w0 = (u & 15) * 8;
    const int grow = h0 - 1 + row;
    const int cloc = ch & 7;
    const int gch = (ch < 8) ? (c0 + cloc) : (HID + c0 + cloc);
    us8 v;
    #pragma unroll
    for (int t = 0; t < 8; ++t) v.u[t] = 0;
    if (c0 + cloc < HID && grow >= 0 && grow < HHH)
      v = *reinterpret_cast<const us8*>(Hb + (size_t)gch * NPIX + grow * WWW + w0);
    *reinterpret_cast<us8*>(&hs[ch][row][w0]) = v;
  }
  __syncthreads();

  const int q = tid & 63;
  const int jp = tid >> 6;
  const int px_l = q * 4;
  const int dh = px_l >> 7;
  const int w = px_l & 127;

  #pragma unroll
  for (int jj = 0; jj < 2; ++jj) {
    const int j = jp * 2 + jj;
    uint32 p0 = 0, p1 = 0;
    if (j < npairs) {
      const float* w1 = fdw + (size_t)(c0 + j) * 9;
      const float* w2 = fdw + (size_t)(HID + c0 + j) * 9;
      float x1[4], x2[4];
      const float b1 = fdb[c0 + j], b2 = fdb[HID + c0 + j];
      #pragma unroll
      for (int i = 0; i < 4; ++i) { x1[i] = b1; x2[i] = b2; }
      #pragma unroll
      for (int dy = 0; dy < 3; ++dy) {
        const int row = dh + dy;
        const ushort* r1 = &hs[j][row][0];
        const ushort* r2 = &hs[8 + j][row][0];
        const float am1 = (w > 0) ? bf2f(r1[w - 1]) : 0.f;
        const float am2 = (w > 0) ? bf2f(r2[w - 1]) : 0.f;
        const us4 c1 = *reinterpret_cast<const us4*>(&r1[w]);
        const us4 c2 = *reinterpret_cast<const us4*>(&r2[w]);
        const float ap1 = (w < 124) ? bf2f(r1[w + 4]) : 0.f;
        const float ap2 = (w < 124) ? bf2f(r2[w + 4]) : 0.f;
        const float e10 = bf2f(c1.u[0]), e11 = bf2f(c1.u[1]);
        const float e12 = bf2f(c1.u[2]), e13 = bf2f(c1.u[3]);
        const float e20 = bf2f(c2.u[0]), e21 = bf2f(c2.u[1]);
        const float e22 = bf2f(c2.u[2]), e23 = bf2f(c2.u[3]);
        const float wa0 = w1[dy * 3 + 0], wa1 = w1[dy * 3 + 1], wa2 = w1[dy * 3 + 2];
        const float wb0 = w2[dy * 3 + 0], wb1 = w2[dy * 3 + 1], wb2 = w2[dy * 3 + 2];
        x1[0] += wa0 * am1 + wa1 * e10 + wa2 * e11;
        x1[1] += wa0 * e10 + wa1 * e11 + wa2 * e12;
        x1[2] += wa0 * e11 + wa1 * e12 + wa2 * e13;
        x1[3] += wa0 * e12 + wa1 * e13 + wa2 * ap1;
        x2[0] += wb0 * am2 + wb1 * e20 + wb2 * e21;
        x2[1] += wb0 * e20 + wb1 * e21 + wb2 * e22;
        x2[2] += wb0 * e21 + wb1 * e22 + wb2 * e23;
        x2[3] += wb0 * e22 + wb1 * e23 + wb2 * ap2;
      }
      const ushort v0 = f2bf(x1[0] * gelu_exact(x2[0]));
      const ushort v1 = f2bf(x1[1] * gelu_exact(x2[1]));
      const ushort v2 = f2bf(x1[2] * gelu_exact(x2[2]));
      const ushort v3 = f2bf(x1[3] * gelu_exact(x2[3]));
      p0 = (uint32)v0 | ((uint32)v1 << 16);
      p1 = (uint32)v2 | ((uint32)v3 << 16);
    }
    gsd[j * 129 + (px_l >> 1)] = p0;
    gsd[j * 129 + (px_l >> 1) + 1] = p1;
  }
  __syncthreads();

  const ushort* gsu = (const ushort*)gsd;
  const int px_l2 = tid;
  const int px = (h0 + (px_l2 >> 7)) * WWW + (px_l2 & 127);
  us8 v;
  #pragma unroll
  for (int t = 0; t < 8; ++t) v.u[t] = gsu[t * 258 + px_l2];
  *reinterpret_cast<us8*>(gt + ((size_t)z * NPIX + px) * 512 + c0) = v;
}

// ================= launch =================
// Workspace lifetimes (P = 25,165,824; peak 185.1 MB):
//  Qt [0,2P) -> dead after q stage-1
//  Fnt [2P,4P) -> dead after merged kv stage-1
//  qh [4P,5P) ql [5P,6P) -> dead after attn
//  vtmp fp32 [0,2P) (over Qt) -> dead after dw-v
//  vbuf fp32 [2P,4P) (over Fnt) -> dead after Fa gemm (read directly by k_nt3fa)
//  kh [0,P) kl [P,2P) (over vtmp, after dw-v) -> dead after attn
//  smalls [6P,6P+10.8M) incl pq/pk -> dead after Fa gemm
//  Fa [4P,6P) (over qh/ql), live to end;  xnt [0,P) (over kh)
//  h2 [P,P+67.1M) (ends 92.3M, vbuf dead by then);  gt2 [6P,6P+33.6M)
//  fiwb/fowb after gt2
extern "C" void kernel_launch(void* const* d_in, const int* in_sizes, int n_in,
                              void* d_out, int out_size, void* d_ws, size_t ws_size,
                              hipStream_t stream)
{
  const float* Q    = (const float*)d_in[0];
  const float* Fn   = (const float*)d_in[1];
  const float* temp = (const float*)d_in[2];
  const float* qw1  = (const float*)d_in[3];
  const float* qb1  = (const float*)d_in[4];
  const float* qw2  = (const float*)d_in[5];
  const float* qb2  = (const float*)d_in[6];
  const float* kw1  = (const float*)d_in[7];
  const float* kb1  = (const float*)d_in[8];
  const float* kw2  = (const float*)d_in[9];
  const float* kb2  = (const float*)d_in[10];
  const float* vw1  = (const float*)d_in[11];
  const float* vb1  = (const float*)d_in[12];
  const float* vw2  = (const float*)d_in[13];
  const float* vb2  = (const float*)d_in[14];
  const float* ow   = (const float*)d_in[15];
  const float* ob   = (const float*)d_in[16];
  const float* lnw  = (const float*)d_in[17];
  const float* lnb  = (const float*)d_in[18];
  const float* fiw  = (const float*)d_in[19];
  const float* fib  = (const float*)d_in[20];
  const float* fdw  = (const float*)d_in[21];
  const float* fdb  = (const float*)d_in[22];
  const float* fow  = (const float*)d_in[23];
  const float* fob  = (const float*)d_in[24];
  float* out = (float*)d_out;

  char* ws = (char*)d_ws;
  const size_t P = 25165824UL;
  ushort* Qth = (ushort*)(ws + 0 * P);
  ushort* Qtl = (ushort*)(ws + 1 * P);
  ushort* Fth = (ushort*)(ws + 2 * P);
  ushort* Ftl = (ushort*)(ws + 3 * P);
  ushort* qh  = (ushort*)(ws + 4 * P);
  ushort* ql  = (ushort*)(ws + 5 * P);
  float*  vtmp = (float*)(ws + 0 * P);   // v stage-1 out (over Qt)
  float*  vbuf = (float*)(ws + 2 * P);   // v after dw (over Fnt), read by k_nt3fa
  ushort* kh  = (ushort*)(ws + 0 * P);   // written after dw-v
  ushort* kl  = (ushort*)(ws + 1 * P);
  char* smb = ws + 6 * P;
  float* rq    = (float*)(smb);
  float* rk    = (float*)(smb + 4096);
  float* part  = (float*)(smb + 8192);
  float* attnm = (float*)(smb + 8192 + 9437184);
  float* Mm    = (float*)(smb + 8192 + 9437184 + 589824);
  float* pq    = (float*)(smb + 8192 + 9437184 + 2 * 589824);
  float* pk    = (float*)(smb + 8192 + 9437184 + 2 * 589824 + 49152);
  float*  Fa   = (float*)(ws + 4 * P);
  ushort* xnt  = (ushort*)(ws + 0 * P);
  ushort* h2   = (ushort*)(ws + 1 * P);
  ushort* gt2  = (ushort*)(ws + 6 * P);
  ushort* fiwb = (ushort*)(ws + 6 * P + 33554432UL);
  ushort* fowb = (ushort*)(ws + 6 * P + 33554432UL + 393216UL);
  float* bufT = out;

  dim3 blk(256);
  dim3 blk512(512);

  // weight preconvert + input transpose-splits
  k_wconv<<<dim3(1152), blk, 0, stream>>>(fiw, fow, fiwb, fowb);
  k_tsplit<<<dim3(64, 3, BB), blk, 0, stream>>>(Q,  Qth, Qtl);
  k_tsplit<<<dim3(64, 3, BB), blk, 0, stream>>>(Fn, Fth, Ftl);
  // q stage-1 + dw(+norm partials)
  k_nt3res<<<dim3(128, 3, BB), blk512, 0, stream>>>(qw1, Qth, Qtl, qb1, bufT, 0);
  k_dw3x3_split<<<dim3(16, CC, BB), blk, 0, stream>>>(bufT, qw2, qb2, qh, ql, pq);
  // merged k+v stage-1; dw-v; dw-k(+partials)
  k_nt3res2<<<dim3(128, 6, BB), blk512, 0, stream>>>(kw1, vw1, Fth, Ftl,
                                                     kb1, vb1, bufT, vtmp);
  k_dw3x3<<<dim3(16, CC, BB), blk, 0, stream>>>(vtmp, vw2, vb2, vbuf);
  k_dw3x3_split<<<dim3(16, CC, BB), blk, 0, stream>>>(bufT, kw2, kb2, kh, kl, pk);
  // norms (from fused partials) + attention
  k_rnfin<<<dim3(3, 2), blk, 0, stream>>>(pq, pk, rq, rk);
  k_attn_mfma<<<dim3(9, KSPLIT, BB), blk, 0, stream>>>(qh, ql, kh, kl, part);
  k_softmax_topk<<<dim3(CC, BB), dim3(192), 0, stream>>>(part, rq, rk, temp, attnm);
  k_mix<<<dim3(CC, BB), dim3(192), 0, stream>>>(ow, attnm, Mm);
  // Fa = Mm @ v + ob  (reads vbuf fp32 directly; no tsplit pass)
  k_nt3fa<<<dim3(128, 3, BB), blk512, 0, stream>>>(Mm, vbuf, ob, Fa);
  // LN -> xnt
  k_ln_t<<<dim3(64, BB), blk, 0, stream>>>(Fa, lnw, lnb, xnt);
  // FFN in 2-batch pairs: fi -> dwglu -> fo
  for (int p = 0; p < 2; ++p) {
    const ushort* xn_p = xnt + (size_t)(2 * p) * NPIX * CC;
    const float*  fa_p = Fa + (size_t)(2 * p) * CC * NPIX;
    float* out_p = out + (size_t)(2 * p) * CC * NPIX;
    k_fi<<<dim3(128, 16, 2), blk, 0, stream>>>(fiwb, xn_p, fib, h2);
    k_dwglu3<<<dim3(64, 64, 2), blk, 0, stream>>>(h2, fdw, fdb, gt2);
    k_fo<<<dim3(128, 3, 2), blk, 0, stream>>>(fowb, gt2, fob, fa_p, out_p);
  }
}

// Round 16
// 622.579 us; speedup vs baseline: 1.0010x; 1.0010x over previous
//
#include <hip/hip_runtime.h>
#include <math.h>
#include <float.h>

#define NPIX 16384
#define CC 192
#define BB 4
#define HHH 128
#define WWW 128
#define HID 510
#define HID2 1020
#define KKEEP 172
#define KSPLIT 16

typedef unsigned short ushort;
typedef unsigned int uint32;
using f32x4  = __attribute__((ext_vector_type(4))) float;
using bf16x8 = __attribute__((ext_vector_type(8))) short;

__device__ __forceinline__ float bf2f(ushort u) {
  union { float f; unsigned int i; } x; x.i = ((unsigned int)u) << 16; return x.f;
}
__device__ __forceinline__ ushort f2bf(float f) {
  union { float f; unsigned int i; } x; x.f = f;
  unsigned int r = (x.i + 0x7FFFu + ((x.i >> 16) & 1u)) >> 16;
  return (ushort)r;
}

struct __align__(16) us8 { ushort u[8]; };
struct __align__(8)  us4 { ushort u[4]; };

// ================= weight preconvert =================
__global__ __launch_bounds__(256) void k_wconv(
    const float* __restrict__ fiw, const float* __restrict__ fow,
    ushort* __restrict__ fiwb, ushort* __restrict__ fowb)
{
  const int idx = blockIdx.x * 256 + threadIdx.x;
  if (idx < 1024 * 192) {
    const int r = idx / 192, c = idx % 192;
    fiwb[idx] = (r < HID2) ? f2bf(fiw[r * 192 + c]) : (ushort)0;
  }
  const int i2 = idx - 1024 * 192;
  if (i2 >= 0 && i2 < 192 * 512) {
    const int r = i2 / 512, c = i2 % 512;
    fowb[i2] = (c < HID) ? f2bf(fow[r * HID + c]) : (ushort)0;
  }
}

// ================= transpose+split: fp32 [C][NPIX] -> hi/lo bf16 [NPIX][192] ==
__global__ __launch_bounds__(256) void k_tsplit(
    const float* __restrict__ X, ushort* __restrict__ Xh, ushort* __restrict__ Xl)
{
  __shared__ float ld[64][261];
  const int b = blockIdx.z;
  const int c0 = blockIdx.y * 64;
  const int px0 = blockIdx.x * 256;
  const int tid = threadIdx.x;
  #pragma unroll
  for (int i = 0; i < 16; ++i) {
    const int u = i * 256 + tid;
    const int r = u >> 6, p4 = (u & 63) * 4;
    const float4 v = *reinterpret_cast<const float4*>(
        X + ((size_t)b * CC + c0 + r) * NPIX + px0 + p4);
    ld[r][p4] = v.x; ld[r][p4 + 1] = v.y; ld[r][p4 + 2] = v.z; ld[r][p4 + 3] = v.w;
  }
  __syncthreads();
  const int c8 = (tid & 7) * 8;
  #pragma unroll
  for (int it = 0; it < 8; ++it) {
    const int pl = it * 32 + (tid >> 3);
    us8 hi, lo;
    #pragma unroll
    for (int j = 0; j < 8; ++j) {
      const float v = ld[c8 + j][pl];
      const ushort h = f2bf(v);
      hi.u[j] = h; lo.u[j] = f2bf(v - bf2f(h));
    }
    const size_t off = ((size_t)b * NPIX + px0 + pl) * CC + c0 + c8;
    *reinterpret_cast<us8*>(Xh + off) = hi;
    *reinterpret_cast<us8*>(Xl + off) = lo;
  }
}

// ===== resident NT 3-pass GEMM, 16-wave (1024 thr): q stage-1 ================
// 64m x 128n, K=192 resident, one barrier. Wave tile 16x32 (4m x 4n waves).
__global__ __launch_bounds__(1024) void k_nt3res(
    const float* __restrict__ W,
    const ushort* __restrict__ Bh, const ushort* __restrict__ Bl,
    const float* __restrict__ bias, float* __restrict__ C,
    long long sAb)
{
  __shared__ ushort As[2][64][200];
  __shared__ ushort Bs[2][128][200];
  const int b = blockIdx.z;
  const int n0 = blockIdx.x * 128;
  const int m0 = blockIdx.y * 64;
  const int tid = threadIdx.x;
  const int lane = tid & 63;
  const int wave = tid >> 6;          // 0..15
  const int wm = wave >> 2, wn = wave & 3;
  const float*  Wb  = W  + (size_t)b * sAb;
  const ushort* Bhb = Bh + (size_t)b * NPIX * CC;
  const ushort* Blb = Bl + (size_t)b * NPIX * CC;

  #pragma unroll
  for (int i = 0; i < 3; ++i) {
    const int u = i * 1024 + tid;
    const int r = u / 48, c = (u % 48) * 4;
    const float4 v = *reinterpret_cast<const float4*>(Wb + (size_t)(m0 + r) * CC + c);
    const float e[4] = {v.x, v.y, v.z, v.w};
    us4 hi, lo;
    #pragma unroll
    for (int t = 0; t < 4; ++t) {
      const ushort h = f2bf(e[t]);
      hi.u[t] = h; lo.u[t] = f2bf(e[t] - bf2f(h));
    }
    *reinterpret_cast<us4*>(&As[0][r][c]) = hi;
    *reinterpret_cast<us4*>(&As[1][r][c]) = lo;
  }
  #pragma unroll
  for (int i = 0; i < 3; ++i) {
    const int u = i * 1024 + tid;
    const int r = u / 24, c = (u % 24) * 8;
    *reinterpret_cast<us8*>(&Bs[0][r][c]) =
        *reinterpret_cast<const us8*>(Bhb + (size_t)(n0 + r) * CC + c);
    *reinterpret_cast<us8*>(&Bs[1][r][c]) =
        *reinterpret_cast<const us8*>(Blb + (size_t)(n0 + r) * CC + c);
  }
  __syncthreads();

  f32x4 acc[2];
  acc[0] = (f32x4){0.f, 0.f, 0.f, 0.f};
  acc[1] = (f32x4){0.f, 0.f, 0.f, 0.f};

  #pragma unroll
  for (int kk = 0; kk < 6; ++kk) {
    bf16x8 af[2], bfg[2][2];
    #pragma unroll
    for (int p = 0; p < 2; ++p)
      af[p] = *reinterpret_cast<const bf16x8*>(
          &As[p][wm * 16 + (lane & 15)][kk * 32 + (lane >> 4) * 8]);
    #pragma unroll
    for (int ni = 0; ni < 2; ++ni)
      #pragma unroll
      for (int p = 0; p < 2; ++p)
        bfg[ni][p] = *reinterpret_cast<const bf16x8*>(
            &Bs[p][wn * 32 + ni * 16 + (lane & 15)][kk * 32 + (lane >> 4) * 8]);
    #pragma unroll
    for (int ni = 0; ni < 2; ++ni) {
      acc[ni] = __builtin_amdgcn_mfma_f32_16x16x32_bf16(af[0], bfg[ni][0], acc[ni], 0, 0, 0);
      acc[ni] = __builtin_amdgcn_mfma_f32_16x16x32_bf16(af[0], bfg[ni][1], acc[ni], 0, 0, 0);
      acc[ni] = __builtin_amdgcn_mfma_f32_16x16x32_bf16(af[1], bfg[ni][0], acc[ni], 0, 0, 0);
    }
  }

  #pragma unroll
  for (int r = 0; r < 4; ++r) {
    const int m = m0 + wm * 16 + (lane >> 4) * 4 + r;
    const float bv = bias[m];
    #pragma unroll
    for (int ni = 0; ni < 2; ++ni) {
      const int n = n0 + wn * 32 + ni * 16 + (lane & 15);
      C[(size_t)b * CC * NPIX + (size_t)m * NPIX + n] = acc[ni][r] + bv;
    }
  }
}

// ====== Fa GEMM, 16-wave: B = fp32 v [c][px], transposed+split in staging ====
__global__ __launch_bounds__(1024) void k_nt3fa(
    const float* __restrict__ W, const float* __restrict__ V,
    const float* __restrict__ bias, float* __restrict__ C)
{
  __shared__ ushort As[2][64][200];
  __shared__ ushort Bs[2][128][200];
  const int b = blockIdx.z;
  const int n0 = blockIdx.x * 128;
  const int m0 = blockIdx.y * 64;
  const int tid = threadIdx.x;
  const int lane = tid & 63;
  const int wave = tid >> 6;
  const int wm = wave >> 2, wn = wave & 3;
  const float* Wb = W + (size_t)b * CC * CC;
  const float* Vb = V + (size_t)b * CC * NPIX;

  #pragma unroll
  for (int i = 0; i < 3; ++i) {
    const int u = i * 1024 + tid;
    const int r = u / 48, c = (u % 48) * 4;
    const float4 v = *reinterpret_cast<const float4*>(Wb + (size_t)(m0 + r) * CC + c);
    const float e[4] = {v.x, v.y, v.z, v.w};
    us4 hi, lo;
    #pragma unroll
    for (int t = 0; t < 4; ++t) {
      const ushort h = f2bf(e[t]);
      hi.u[t] = h; lo.u[t] = f2bf(e[t] - bf2f(h));
    }
    *reinterpret_cast<us4*>(&As[0][r][c]) = hi;
    *reinterpret_cast<us4*>(&As[1][r][c]) = lo;
  }
  // B: 6 chunks of [32c][128px]; two 512-thread halves handle 3 chunks each
  {
    const int half = tid >> 9;
    const int krp = (tid & 511) >> 5;     // 0..15
    const int n4 = (tid & 31) * 4;
    #pragma unroll
    for (int i = 0; i < 3; ++i) {
      const int kk0 = half * 96 + i * 32;
      const float4 f0 = *reinterpret_cast<const float4*>(
          Vb + (size_t)(kk0 + 2 * krp) * NPIX + n0 + n4);
      const float4 f1 = *reinterpret_cast<const float4*>(
          Vb + (size_t)(kk0 + 2 * krp + 1) * NPIX + n0 + n4);
      const float e0[4] = {f0.x, f0.y, f0.z, f0.w};
      const float e1[4] = {f1.x, f1.y, f1.z, f1.w};
      #pragma unroll
      for (int j = 0; j < 4; ++j) {
        const ushort h0 = f2bf(e0[j]), h1 = f2bf(e1[j]);
        const ushort l0 = f2bf(e0[j] - bf2f(h0)), l1 = f2bf(e1[j] - bf2f(h1));
        *reinterpret_cast<uint32*>(&Bs[0][n4 + j][kk0 + 2 * krp]) =
            (uint32)h0 | ((uint32)h1 << 16);
        *reinterpret_cast<uint32*>(&Bs[1][n4 + j][kk0 + 2 * krp]) =
            (uint32)l0 | ((uint32)l1 << 16);
      }
    }
  }
  __syncthreads();

  f32x4 acc[2];
  acc[0] = (f32x4){0.f, 0.f, 0.f, 0.f};
  acc[1] = (f32x4){0.f, 0.f, 0.f, 0.f};

  #pragma unroll
  for (int kk = 0; kk < 6; ++kk) {
    bf16x8 af[2], bfg[2][2];
    #pragma unroll
    for (int p = 0; p < 2; ++p)
      af[p] = *reinterpret_cast<const bf16x8*>(
          &As[p][wm * 16 + (lane & 15)][kk * 32 + (lane >> 4) * 8]);
    #pragma unroll
    for (int ni = 0; ni < 2; ++ni)
      #pragma unroll
      for (int p = 0; p < 2; ++p)
        bfg[ni][p] = *reinterpret_cast<const bf16x8*>(
            &Bs[p][wn * 32 + ni * 16 + (lane & 15)][kk * 32 + (lane >> 4) * 8]);
    #pragma unroll
    for (int ni = 0; ni < 2; ++ni) {
      acc[ni] = __builtin_amdgcn_mfma_f32_16x16x32_bf16(af[0], bfg[ni][0], acc[ni], 0, 0, 0);
      acc[ni] = __builtin_amdgcn_mfma_f32_16x16x32_bf16(af[0], bfg[ni][1], acc[ni], 0, 0, 0);
      acc[ni] = __builtin_amdgcn_mfma_f32_16x16x32_bf16(af[1], bfg[ni][0], acc[ni], 0, 0, 0);
    }
  }

  #pragma unroll
  for (int r = 0; r < 4; ++r) {
    const int m = m0 + wm * 16 + (lane >> 4) * 4 + r;
    const float bv = bias[m];
    #pragma unroll
    for (int ni = 0; ni < 2; ++ni) {
      const int n = n0 + wn * 32 + ni * 16 + (lane & 15);
      C[(size_t)b * CC * NPIX + (size_t)m * NPIX + n] = acc[ni][r] + bv;
    }
  }
}

// ================= merged k+v stage-1, 16-wave ================================
__global__ __launch_bounds__(1024) void k_nt3res2(
    const float* __restrict__ W1, const float* __restrict__ W2,
    const ushort* __restrict__ Bh, const ushort* __restrict__ Bl,
    const float* __restrict__ b1, const float* __restrict__ b2,
    float* __restrict__ C1, float* __restrict__ C2)
{
  __shared__ ushort As[2][64][200];
  __shared__ ushort Bs[2][128][200];
  const int b = blockIdx.z;
  const int n0 = blockIdx.x * 128;
  const bool sel = blockIdx.y >= 3;
  const int m0 = (sel ? (blockIdx.y - 3) : blockIdx.y) * 64;
  const float* W = sel ? W2 : W1;
  const float* bias = sel ? b2 : b1;
  float* C = sel ? C2 : C1;
  const int tid = threadIdx.x;
  const int lane = tid & 63;
  const int wave = tid >> 6;
  const int wm = wave >> 2, wn = wave & 3;
  const ushort* Bhb = Bh + (size_t)b * NPIX * CC;
  const ushort* Blb = Bl + (size_t)b * NPIX * CC;

  #pragma unroll
  for (int i = 0; i < 3; ++i) {
    const int u = i * 1024 + tid;
    const int r = u / 48, c = (u % 48) * 4;
    const float4 v = *reinterpret_cast<const float4*>(W + (size_t)(m0 + r) * CC + c);
    const float e[4] = {v.x, v.y, v.z, v.w};
    us4 hi, lo;
    #pragma unroll
    for (int t = 0; t < 4; ++t) {
      const ushort h = f2bf(e[t]);
      hi.u[t] = h; lo.u[t] = f2bf(e[t] - bf2f(h));
    }
    *reinterpret_cast<us4*>(&As[0][r][c]) = hi;
    *reinterpret_cast<us4*>(&As[1][r][c]) = lo;
  }
  #pragma unroll
  for (int i = 0; i < 3; ++i) {
    const int u = i * 1024 + tid;
    const int r = u / 24, c = (u % 24) * 8;
    *reinterpret_cast<us8*>(&Bs[0][r][c]) =
        *reinterpret_cast<const us8*>(Bhb + (size_t)(n0 + r) * CC + c);
    *reinterpret_cast<us8*>(&Bs[1][r][c]) =
        *reinterpret_cast<const us8*>(Blb + (size_t)(n0 + r) * CC + c);
  }
  __syncthreads();

  f32x4 acc[2];
  acc[0] = (f32x4){0.f, 0.f, 0.f, 0.f};
  acc[1] = (f32x4){0.f, 0.f, 0.f, 0.f};

  #pragma unroll
  for (int kk = 0; kk < 6; ++kk) {
    bf16x8 af[2], bfg[2][2];
    #pragma unroll
    for (int p = 0; p < 2; ++p)
      af[p] = *reinterpret_cast<const bf16x8*>(
          &As[p][wm * 16 + (lane & 15)][kk * 32 + (lane >> 4) * 8]);
    #pragma unroll
    for (int ni = 0; ni < 2; ++ni)
      #pragma unroll
      for (int p = 0; p < 2; ++p)
        bfg[ni][p] = *reinterpret_cast<const bf16x8*>(
            &Bs[p][wn * 32 + ni * 16 + (lane & 15)][kk * 32 + (lane >> 4) * 8]);
    #pragma unroll
    for (int ni = 0; ni < 2; ++ni) {
      acc[ni] = __builtin_amdgcn_mfma_f32_16x16x32_bf16(af[0], bfg[ni][0], acc[ni], 0, 0, 0);
      acc[ni] = __builtin_amdgcn_mfma_f32_16x16x32_bf16(af[0], bfg[ni][1], acc[ni], 0, 0, 0);
      acc[ni] = __builtin_amdgcn_mfma_f32_16x16x32_bf16(af[1], bfg[ni][0], acc[ni], 0, 0, 0);
    }
  }

  #pragma unroll
  for (int r = 0; r < 4; ++r) {
    const int m = m0 + wm * 16 + (lane >> 4) * 4 + r;
    const float bv = bias[m];
    #pragma unroll
    for (int ni = 0; ni < 2; ++ni) {
      const int n = n0 + wn * 32 + ni * 16 + (lane & 15);
      C[(size_t)b * CC * NPIX + (size_t)m * NPIX + n] = acc[ni][r] + bv;
    }
  }
}

// ================= fi GEMM v2: 64m x 128n, 76.8 KB LDS — R11-verified ========
__global__ __launch_bounds__(256) void k_fi(
    const ushort* __restrict__ Aw, const ushort* __restrict__ Bt,
    const float* __restrict__ bias, ushort* __restrict__ H)
{
  __shared__ ushort lds[64 * 200 + 128 * 200];
  ushort (*As)[200] = reinterpret_cast<ushort(*)[200]>(lds);
  ushort (*Bs)[200] = reinterpret_cast<ushort(*)[200]>(lds + 64 * 200);
  ushort (*Cs)[132] = reinterpret_cast<ushort(*)[132]>(lds);
  const int z = blockIdx.z;
  const int n0 = blockIdx.x * 128;
  const int m0 = blockIdx.y * 64;
  const int tid = threadIdx.x;
  const int lane = tid & 63;
  const int wave = tid >> 6;
  const int wm = wave >> 1, wn = wave & 1;
  const ushort* Bb = Bt + (size_t)z * NPIX * CC;
  ushort* Hb = H + (size_t)z * 1024 * NPIX;

  #pragma unroll
  for (int i = 0; i < 6; ++i) {
    const int u = i * 256 + tid;
    const int r = u / 24, c = (u % 24) * 8;
    *reinterpret_cast<us8*>(&As[r][c]) =
        *reinterpret_cast<const us8*>(Aw + (size_t)(m0 + r) * CC + c);
  }
  #pragma unroll
  for (int i = 0; i < 12; ++i) {
    const int u = i * 256 + tid;
    const int r = u / 24, c = (u % 24) * 8;
    *reinterpret_cast<us8*>(&Bs[r][c]) =
        *reinterpret_cast<const us8*>(Bb + (size_t)(n0 + r) * CC + c);
  }
  __syncthreads();

  f32x4 acc[2][4];
  #pragma unroll
  for (int i = 0; i < 2; ++i)
    #pragma unroll
    for (int j = 0; j < 4; ++j) acc[i][j] = (f32x4){0.f, 0.f, 0.f, 0.f};

  #pragma unroll
  for (int kk = 0; kk < 6; ++kk) {
    bf16x8 af[2], bfg[4];
    #pragma unroll
    for (int mi = 0; mi < 2; ++mi)
      af[mi] = *reinterpret_cast<const bf16x8*>(
          &As[wm * 32 + mi * 16 + (lane & 15)][kk * 32 + (lane >> 4) * 8]);
    #pragma unroll
    for (int ni = 0; ni < 4; ++ni)
      bfg[ni] = *reinterpret_cast<const bf16x8*>(
          &Bs[wn * 64 + ni * 16 + (lane & 15)][kk * 32 + (lane >> 4) * 8]);
    #pragma unroll
    for (int mi = 0; mi < 2; ++mi)
      #pragma unroll
      for (int ni = 0; ni < 4; ++ni)
        acc[mi][ni] = __builtin_amdgcn_mfma_f32_16x16x32_bf16(
            af[mi], bfg[ni], acc[mi][ni], 0, 0, 0);
  }

  __syncthreads();
  #pragma unroll
  for (int mi = 0; mi < 2; ++mi)
    #pragma unroll
    for (int rr = 0; rr < 4; ++rr) {
      const int rloc = wm * 32 + mi * 16 + (lane >> 4) * 4 + rr;
      const int m = m0 + rloc;
      const float bv = (m < HID2) ? bias[m] : 0.f;
      #pragma unroll
      for (int ni = 0; ni < 4; ++ni) {
        const int cc = wn * 64 + ni * 16 + (lane & 15);
        Cs[rloc][cc] = f2bf(acc[mi][ni][rr] + bv);
      }
    }
  __syncthreads();
  #pragma unroll
  for (int it = 0; it < 4; ++it) {
    const int r = it * 16 + (tid >> 4);
    const int c8 = (tid & 15) * 8;
    *reinterpret_cast<us8*>(Hb + (size_t)(m0 + r) * NPIX + n0 + c8) =
        *reinterpret_cast<const us8*>(&Cs[r][c8]);
  }
}

// ================= fo GEMM: A resident, B double-buffered — R11-verified =====
__global__ __launch_bounds__(256) void k_fo(
    const ushort* __restrict__ Aw, const ushort* __restrict__ Bt,
    const float* __restrict__ bias, const float* __restrict__ res,
    float* __restrict__ C)
{
  __shared__ ushort As[64][520];
  __shared__ ushort Bs[2][128][136];
  const int z = blockIdx.z;
  const int n0 = blockIdx.x * 128;
  const int m0 = blockIdx.y * 64;
  const int tid = threadIdx.x;
  const int lane = tid & 63;
  const int wave = tid >> 6;
  const int wm = wave >> 1, wn = wave & 1;
  const ushort* Bb = Bt + (size_t)z * NPIX * 512;
  const float* resb = res + (size_t)z * CC * NPIX;
  float* Cb = C + (size_t)z * CC * NPIX;

  #pragma unroll
  for (int i = 0; i < 16; ++i) {
    const int u = i * 256 + tid;
    const int r = u >> 6, c = (u & 63) * 8;
    *reinterpret_cast<us8*>(&As[r][c]) =
        *reinterpret_cast<const us8*>(Aw + (size_t)(m0 + r) * 512 + c);
  }
  #pragma unroll
  for (int i = 0; i < 8; ++i) {
    const int u = i * 256 + tid;
    const int r = u >> 4, c = (u & 15) * 8;
    *reinterpret_cast<us8*>(&Bs[0][r][c]) =
        *reinterpret_cast<const us8*>(Bb + (size_t)(n0 + r) * 512 + c);
  }
  __syncthreads();

  f32x4 acc[2][4];
  #pragma unroll
  for (int i = 0; i < 2; ++i)
    #pragma unroll
    for (int j = 0; j < 4; ++j) acc[i][j] = (f32x4){0.f, 0.f, 0.f, 0.f};

  for (int t = 0; t < 4; ++t) {
    us8 rg[8];
    if (t < 3) {
      #pragma unroll
      for (int i = 0; i < 8; ++i) {
        const int u = i * 256 + tid;
        const int r = u >> 4, c = (u & 15) * 8;
        rg[i] = *reinterpret_cast<const us8*>(
            Bb + (size_t)(n0 + r) * 512 + (t + 1) * 128 + c);
      }
    }
    const int cur = t & 1;
    #pragma unroll
    for (int ks = 0; ks < 4; ++ks) {
      bf16x8 af[2], bfg[4];
      #pragma unroll
      for (int mi = 0; mi < 2; ++mi)
        af[mi] = *reinterpret_cast<const bf16x8*>(
            &As[wm * 32 + mi * 16 + (lane & 15)][t * 128 + ks * 32 + (lane >> 4) * 8]);
      #pragma unroll
      for (int ni = 0; ni < 4; ++ni)
        bfg[ni] = *reinterpret_cast<const bf16x8*>(
            &Bs[cur][wn * 64 + ni * 16 + (lane & 15)][ks * 32 + (lane >> 4) * 8]);
      #pragma unroll
      for (int mi = 0; mi < 2; ++mi)
        #pragma unroll
        for (int ni = 0; ni < 4; ++ni)
          acc[mi][ni] = __builtin_amdgcn_mfma_f32_16x16x32_bf16(
              af[mi], bfg[ni], acc[mi][ni], 0, 0, 0);
    }
    if (t < 3) {
      #pragma unroll
      for (int i = 0; i < 8; ++i) {
        const int u = i * 256 + tid;
        const int r = u >> 4, c = (u & 15) * 8;
        *reinterpret_cast<us8*>(&Bs[cur ^ 1][r][c]) = rg[i];
      }
    }
    __syncthreads();
  }

  #pragma unroll
  for (int mi = 0; mi < 2; ++mi)
    #pragma unroll
    for (int r = 0; r < 4; ++r) {
      const int m = m0 + wm * 32 + mi * 16 + (lane >> 4) * 4 + r;
      const float bv = bias[m];
      #pragma unroll
      for (int ni = 0; ni < 4; ++ni) {
        const int n = n0 + wn * 64 + ni * 16 + (lane & 15);
        Cb[(size_t)m * NPIX + n] = acc[mi][ni][r] + bv + resb[(size_t)m * NPIX + n];
      }
    }
}

// ================= attn logits: MFMA 3-pass split-K — verified ===============
__global__ __launch_bounds__(256) void k_attn_mfma(
    const ushort* __restrict__ qh, const ushort* __restrict__ ql,
    const ushort* __restrict__ kh, const ushort* __restrict__ kl,
    float* __restrict__ part)
{
  __shared__ ushort As[2][64][40];
  __shared__ ushort Bs[2][64][40];
  const int b = blockIdx.z;
  const int tr = blockIdx.x / 3, tc = blockIdx.x % 3;
  const int r0 = tr * 64, c0 = tc * 64;
  const int k0 = blockIdx.y * (NPIX / KSPLIT);
  const int tid = threadIdx.x;
  const int lane = tid & 63;
  const int wave = tid >> 6;
  const int wm = wave >> 1, wn = wave & 1;

  f32x4 acc[2][2];
  #pragma unroll
  for (int i = 0; i < 2; ++i)
    #pragma unroll
    for (int j = 0; j < 2; ++j) acc[i][j] = (f32x4){0.f, 0.f, 0.f, 0.f};

  const int ar = tid >> 2, ak = (tid & 3) * 8;

  for (int kc = 0; kc < NPIX / KSPLIT; kc += 32) {
    const size_t qo = (size_t)(b * CC + r0 + ar) * NPIX + k0 + kc + ak;
    const size_t ko = (size_t)(b * CC + c0 + ar) * NPIX + k0 + kc + ak;
    *reinterpret_cast<us8*>(&As[0][ar][ak]) = *reinterpret_cast<const us8*>(qh + qo);
    *reinterpret_cast<us8*>(&As[1][ar][ak]) = *reinterpret_cast<const us8*>(ql + qo);
    *reinterpret_cast<us8*>(&Bs[0][ar][ak]) = *reinterpret_cast<const us8*>(kh + ko);
    *reinterpret_cast<us8*>(&Bs[1][ar][ak]) = *reinterpret_cast<const us8*>(kl + ko);
    __syncthreads();
    bf16x8 af[2][2], bfr[2][2];
    #pragma unroll
    for (int mi = 0; mi < 2; ++mi)
      #pragma unroll
      for (int p = 0; p < 2; ++p)
        af[mi][p] = *reinterpret_cast<const bf16x8*>(
            &As[p][wm * 32 + mi * 16 + (lane & 15)][(lane >> 4) * 8]);
    #pragma unroll
    for (int ni = 0; ni < 2; ++ni)
      #pragma unroll
      for (int p = 0; p < 2; ++p)
        bfr[ni][p] = *reinterpret_cast<const bf16x8*>(
            &Bs[p][wn * 32 + ni * 16 + (lane & 15)][(lane >> 4) * 8]);
    #pragma unroll
    for (int mi = 0; mi < 2; ++mi)
      #pragma unroll
      for (int ni = 0; ni < 2; ++ni) {
        acc[mi][ni] = __builtin_amdgcn_mfma_f32_16x16x32_bf16(
            af[mi][0], bfr[ni][0], acc[mi][ni], 0, 0, 0);
        acc[mi][ni] = __builtin_amdgcn_mfma_f32_16x16x32_bf16(
            af[mi][0], bfr[ni][1], acc[mi][ni], 0, 0, 0);
        acc[mi][ni] = __builtin_amdgcn_mfma_f32_16x16x32_bf16(
            af[mi][1], bfr[ni][0], acc[mi][ni], 0, 0, 0);
      }
    __syncthreads();
  }

  float* pp = part + (size_t)(blockIdx.y * BB + b) * CC * CC;
  #pragma unroll
  for (int mi = 0; mi < 2; ++mi)
    #pragma unroll
    for (int r = 0; r < 4; ++r) {
      const int row = r0 + wm * 32 + mi * 16 + (lane >> 4) * 4 + r;
      #pragma unroll
      for (int ni = 0; ni < 2; ++ni) {
        const int col = c0 + wn * 32 + ni * 16 + (lane & 15);
        pp[(size_t)row * CC + col] = acc[mi][ni][r];
      }
    }
}

// ================= depthwise 3x3 helper =================
__device__ __forceinline__ void dw4(const float* __restrict__ Xc,
                                    const float* __restrict__ wt, float bv,
                                    int h, int w, float out[4])
{
  float a0, a1, a2, a3;
  a0 = a1 = a2 = a3 = bv;
  #pragma unroll
  for (int dy = 0; dy < 3; ++dy) {
    const int hh = h + dy - 1;
    if (hh < 0 || hh >= HHH) continue;
    const float* row = Xc + hh * WWW + w;
    const float xm = (w > 0) ? row[-1] : 0.f;
    const float4 xc = *reinterpret_cast<const float4*>(row);
    const float xp = (w < WWW - 4) ? row[4] : 0.f;
    const float w0 = wt[dy * 3 + 0], w1 = wt[dy * 3 + 1], w2 = wt[dy * 3 + 2];
    a0 += w0 * xm   + w1 * xc.x + w2 * xc.y;
    a1 += w0 * xc.x + w1 * xc.y + w2 * xc.z;
    a2 += w0 * xc.y + w1 * xc.z + w2 * xc.w;
    a3 += w0 * xc.z + w1 * xc.w + w2 * xp;
  }
  out[0] = a0; out[1] = a1; out[2] = a2; out[3] = a3;
}

// plain dw3x3 (v path) — R11-verified
__global__ __launch_bounds__(256) void k_dw3x3(
    const float* __restrict__ X, const float* __restrict__ W9,
    const float* __restrict__ bias, float* __restrict__ Y)
{
  const int b = blockIdx.z, c = blockIdx.y;
  const int p = blockIdx.x * 1024 + threadIdx.x * 4;
  const int h = p >> 7, w = p & 127;
  float o[4];
  dw4(X + (size_t)(b * CC + c) * NPIX, W9 + c * 9, bias[c], h, w, o);
  *reinterpret_cast<float4*>(Y + (size_t)(b * CC + c) * NPIX + p) =
      make_float4(o[0], o[1], o[2], o[3]);
}

// dw3x3 + hi/lo split planes [c][px] + row-norm partials (fused) — verified
__global__ __launch_bounds__(256) void k_dw3x3_split(
    const float* __restrict__ X, const float* __restrict__ W9,
    const float* __restrict__ bias, ushort* __restrict__ Yh,
    ushort* __restrict__ Yl, float* __restrict__ partial)
{
  const int b = blockIdx.z, c = blockIdx.y;
  const int p = blockIdx.x * 1024 + threadIdx.x * 4;
  const int h = p >> 7, w = p & 127;
  float o[4];
  dw4(X + (size_t)(b * CC + c) * NPIX, W9 + c * 9, bias[c], h, w, o);
  us4 hi, lo;
  #pragma unroll
  for (int t = 0; t < 4; ++t) {
    const ushort hv = f2bf(o[t]);
    hi.u[t] = hv;
    lo.u[t] = f2bf(o[t] - bf2f(hv));
  }
  const size_t off = (size_t)(b * CC + c) * NPIX + p;
  *reinterpret_cast<us4*>(Yh + off) = hi;
  *reinterpret_cast<us4*>(Yl + off) = lo;
  __shared__ float sm[256];
  sm[threadIdx.x] = o[0]*o[0] + o[1]*o[1] + o[2]*o[2] + o[3]*o[3];
  __syncthreads();
  for (int st = 128; st > 0; st >>= 1) {
    if (threadIdx.x < st) sm[threadIdx.x] += sm[threadIdx.x + st];
    __syncthreads();
  }
  if (threadIdx.x == 0)
    partial[(size_t)(b * CC + c) * 16 + blockIdx.x] = sm[0];
}

// finalize reciprocal norms from partials (fixed order -> deterministic)
__global__ __launch_bounds__(256) void k_rnfin(
    const float* __restrict__ pq, const float* __restrict__ pk,
    float* __restrict__ rq, float* __restrict__ rk)
{
  const int row = blockIdx.x * 256 + threadIdx.x;
  if (row >= BB * CC) return;
  const float* p = blockIdx.y ? pk : pq;
  float s = 0.f;
  for (int i = 0; i < 16; ++i) s += p[(size_t)row * 16 + i];
  (blockIdx.y ? rk : rq)[row] = 1.f / fmaxf(sqrtf(s), 1e-12f);
}

// ================= softmax + topk mask =================
__global__ __launch_bounds__(192) void k_softmax_topk(
    const float* __restrict__ part, const float* __restrict__ rq,
    const float* __restrict__ rk, const float* __restrict__ temp,
    float* __restrict__ attnm)
{
  const int c = blockIdx.x, b = blockIdx.y, d = threadIdx.x;
  float s = 0.f;
  for (int ksp = 0; ksp < KSPLIT; ++ksp)
    s += part[(size_t)(ksp * BB + b) * CC * CC + c * CC + d];
  const float logit = s * rq[b * CC + c] * rk[b * CC + d] * temp[0];
  __shared__ float sa[CC], sb[CC];
  sa[d] = logit; __syncthreads();
  float mx = -FLT_MAX;
  for (int j = 0; j < CC; ++j) mx = fmaxf(mx, sa[j]);
  const float e = expf(logit - mx);
  sb[d] = e; __syncthreads();
  float sum = 0.f;
  for (int j = 0; j < CC; ++j) sum += sb[j];
  const float pv = e / sum;
  __syncthreads();
  sa[d] = pv; __syncthreads();
  int greater = 0;
  for (int j = 0; j < CC; ++j) greater += (sa[j] > pv) ? 1 : 0;
  const float cand = (greater < KKEEP) ? pv : FLT_MAX;
  sb[d] = cand; __syncthreads();
  float thr = FLT_MAX;
  for (int j = 0; j < CC; ++j) thr = fminf(thr, sb[j]);
  attnm[(size_t)(b * CC + c) * CC + d] = (pv >= thr) ? pv : 0.f;
}

// ================= M[b] = ow @ attnm[b] =================
__global__ __launch_bounds__(192) void k_mix(
    const float* __restrict__ ow, const float* __restrict__ attnm,
    float* __restrict__ M)
{
  const int c = blockIdx.x, b = blockIdx.y, d = threadIdx.x;
  float acc = 0.f;
  for (int e = 0; e < CC; ++e)
    acc += ow[c * CC + e] * attnm[(size_t)(b * CC + e) * CC + d];
  M[(size_t)(b * CC + c) * CC + d] = acc;
}

// ================= LayerNorm -> transposed bf16 [px][192] =================
__global__ __launch_bounds__(256) void k_ln_t(
    const float* __restrict__ X, const float* __restrict__ lw,
    const float* __restrict__ lb, ushort* __restrict__ Y)
{
  const int b = blockIdx.y;
  const int n = blockIdx.x * 256 + threadIdx.x;
  const float* Xb = X + (size_t)b * CC * NPIX + n;
  float s = 0.f, s2 = 0.f;
  for (int ci = 0; ci < CC; ++ci) {
    const float v = Xb[(size_t)ci * NPIX];
    s += v; s2 += v * v;
  }
  const float mu = s * (1.f / CC);
  const float var = fmaxf(s2 * (1.f / CC) - mu * mu, 0.f);
  const float rstd = rsqrtf(var + 1e-5f);
  ushort* Yb = Y + ((size_t)b * NPIX + n) * CC;
  for (int c8 = 0; c8 < CC / 8; ++c8) {
    bf16x8 sv;
    #pragma unroll
    for (int t = 0; t < 8; ++t) {
      const int c = c8 * 8 + t;
      const float v = Xb[(size_t)c * NPIX];
      sv[t] = (short)f2bf((v - mu) * rstd * lw[c] + lb[c]);
    }
    *reinterpret_cast<bf16x8*>(Yb + c8 * 8) = sv;
  }
}

// ================= fused depthwise 3x3 + GLU v3 — verified R8 ================
__device__ __forceinline__ float gelu_exact(float x) {
  return 0.5f * x * (1.f + erff(x * 0.70710678118654752f));
}

__global__ __launch_bounds__(256) void k_dwglu3(
    const ushort* __restrict__ Hp, const float* __restrict__ fdw,
    const float* __restrict__ fdb, ushort* __restrict__ gt)
{
  __shared__ ushort hs[16][4][128];
  __shared__ uint32 gsd[8 * 129];
  const int z = blockIdx.z;
  const int c0 = blockIdx.x * 8;
  const int h0 = blockIdx.y * 2;
  const int tid = threadIdx.x;
  const int npairs = min(8, HID - c0);
  const ushort* Hb = Hp + (size_t)z * 1024 * NPIX;

  #pragma unroll
  for (int i = 0; i < 4; ++i) {
    const int u = i * 256 + tid;
    const int ch = u >> 6;
    const int row = (u >> 4) & 3;
    const int w0 = (u & 15) * 8;
    const int grow = h0 - 1 + row;
    const int cloc = ch & 7;
    const int gch = (ch < 8) ? (c0 + cloc) : (HID + c0 + cloc);
    us8 v;
    #pragma unroll
    for (int t = 0; t < 8; ++t) v.u[t] = 0;
    if (c0 + cloc < HID && grow >= 0 && grow < HHH)
      v = *reinterpret_cast<const us8*>(Hb + (size_t)gch * NPIX + grow * WWW + w0);
    *reinterpret_cast<us8*>(&hs[ch][row][w0]) = v;
  }
  __syncthreads();

  const int q = tid & 63;
  const int jp = tid >> 6;
  const int px_l = q * 4;
  const int dh = px_l >> 7;
  const int w = px_l & 127;

  #pragma unroll
  for (int jj = 0; jj < 2; ++jj) {
    const int j = jp * 2 + jj;
    uint32 p0 = 0, p1 = 0;
    if (j < npairs) {
      const float* w1 = fdw + (size_t)(c0 + j) * 9;
      const float* w2 = fdw + (size_t)(HID + c0 + j) * 9;
      float x1[4], x2[4];
      const float b1 = fdb[c0 + j], b2 = fdb[HID + c0 + j];
      #pragma unroll
      for (int i = 0; i < 4; ++i) { x1[i] = b1; x2[i] = b2; }
      #pragma unroll
      for (int dy = 0; dy < 3; ++dy) {
        const int row = dh + dy;
        const ushort* r1 = &hs[j][row][0];
        const ushort* r2 = &hs[8 + j][row][0];
        const float am1 = (w > 0) ? bf2f(r1[w - 1]) : 0.f;
        const float am2 = (w > 0) ? bf2f(r2[w - 1]) : 0.f;
        const us4 c1 = *reinterpret_cast<const us4*>(&r1[w]);
        const us4 c2 = *reinterpret_cast<const us4*>(&r2[w]);
        const float ap1 = (w < 124) ? bf2f(r1[w + 4]) : 0.f;
        const float ap2 = (w < 124) ? bf2f(r2[w + 4]) : 0.f;
        const float e10 = bf2f(c1.u[0]), e11 = bf2f(c1.u[1]);
        const float e12 = bf2f(c1.u[2]), e13 = bf2f(c1.u[3]);
        const float e20 = bf2f(c2.u[0]), e21 = bf2f(c2.u[1]);
        const float e22 = bf2f(c2.u[2]), e23 = bf2f(c2.u[3]);
        const float wa0 = w1[dy * 3 + 0], wa1 = w1[dy * 3 + 1], wa2 = w1[dy * 3 + 2];
        const float wb0 = w2[dy * 3 + 0], wb1 = w2[dy * 3 + 1], wb2 = w2[dy * 3 + 2];
        x1[0] += wa0 * am1 + wa1 * e10 + wa2 * e11;
        x1[1] += wa0 * e10 + wa1 * e11 + wa2 * e12;
        x1[2] += wa0 * e11 + wa1 * e12 + wa2 * e13;
        x1[3] += wa0 * e12 + wa1 * e13 + wa2 * ap1;
        x2[0] += wb0 * am2 + wb1 * e20 + wb2 * e21;
        x2[1] += wb0 * e20 + wb1 * e21 + wb2 * e22;
        x2[2] += wb0 * e21 + wb1 * e22 + wb2 * e23;
        x2[3] += wb0 * e22 + wb1 * e23 + wb2 * ap2;
      }
      const ushort v0 = f2bf(x1[0] * gelu_exact(x2[0]));
      const ushort v1 = f2bf(x1[1] * gelu_exact(x2[1]));
      const ushort v2 = f2bf(x1[2] * gelu_exact(x2[2]));
      const ushort v3 = f2bf(x1[3] * gelu_exact(x2[3]));
      p0 = (uint32)v0 | ((uint32)v1 << 16);
      p1 = (uint32)v2 | ((uint32)v3 << 16);
    }
    gsd[j * 129 + (px_l >> 1)] = p0;
    gsd[j * 129 + (px_l >> 1) + 1] = p1;
  }
  __syncthreads();

  const ushort* gsu = (const ushort*)gsd;
  const int px_l2 = tid;
  const int px = (h0 + (px_l2 >> 7)) * WWW + (px_l2 & 127);
  us8 v;
  #pragma unroll
  for (int t = 0; t < 8; ++t) v.u[t] = gsu[t * 258 + px_l2];
  *reinterpret_cast<us8*>(gt + ((size_t)z * NPIX + px) * 512 + c0) = v;
}

// ================= launch =================
// Workspace layout identical to R15 (peak 185.1 MB, verified).
extern "C" void kernel_launch(void* const* d_in, const int* in_sizes, int n_in,
                              void* d_out, int out_size, void* d_ws, size_t ws_size,
                              hipStream_t stream)
{
  const float* Q    = (const float*)d_in[0];
  const float* Fn   = (const float*)d_in[1];
  const float* temp = (const float*)d_in[2];
  const float* qw1  = (const float*)d_in[3];
  const float* qb1  = (const float*)d_in[4];
  const float* qw2  = (const float*)d_in[5];
  const float* qb2  = (const float*)d_in[6];
  const float* kw1  = (const float*)d_in[7];
  const float* kb1  = (const float*)d_in[8];
  const float* kw2  = (const float*)d_in[9];
  const float* kb2  = (const float*)d_in[10];
  const float* vw1  = (const float*)d_in[11];
  const float* vb1  = (const float*)d_in[12];
  const float* vw2  = (const float*)d_in[13];
  const float* vb2  = (const float*)d_in[14];
  const float* ow   = (const float*)d_in[15];
  const float* ob   = (const float*)d_in[16];
  const float* lnw  = (const float*)d_in[17];
  const float* lnb  = (const float*)d_in[18];
  const float* fiw  = (const float*)d_in[19];
  const float* fib  = (const float*)d_in[20];
  const float* fdw  = (const float*)d_in[21];
  const float* fdb  = (const float*)d_in[22];
  const float* fow  = (const float*)d_in[23];
  const float* fob  = (const float*)d_in[24];
  float* out = (float*)d_out;

  char* ws = (char*)d_ws;
  const size_t P = 25165824UL;
  ushort* Qth = (ushort*)(ws + 0 * P);
  ushort* Qtl = (ushort*)(ws + 1 * P);
  ushort* Fth = (ushort*)(ws + 2 * P);
  ushort* Ftl = (ushort*)(ws + 3 * P);
  ushort* qh  = (ushort*)(ws + 4 * P);
  ushort* ql  = (ushort*)(ws + 5 * P);
  float*  vtmp = (float*)(ws + 0 * P);   // v stage-1 out (over Qt)
  float*  vbuf = (float*)(ws + 2 * P);   // v after dw (over Fnt), read by k_nt3fa
  ushort* kh  = (ushort*)(ws + 0 * P);   // written after dw-v
  ushort* kl  = (ushort*)(ws + 1 * P);
  char* smb = ws + 6 * P;
  float* rq    = (float*)(smb);
  float* rk    = (float*)(smb + 4096);
  float* part  = (float*)(smb + 8192);
  float* attnm = (float*)(smb + 8192 + 9437184);
  float* Mm    = (float*)(smb + 8192 + 9437184 + 589824);
  float* pq    = (float*)(smb + 8192 + 9437184 + 2 * 589824);
  float* pk    = (float*)(smb + 8192 + 9437184 + 2 * 589824 + 49152);
  float*  Fa   = (float*)(ws + 4 * P);
  ushort* xnt  = (ushort*)(ws + 0 * P);
  ushort* h2   = (ushort*)(ws + 1 * P);
  ushort* gt2  = (ushort*)(ws + 6 * P);
  ushort* fiwb = (ushort*)(ws + 6 * P + 33554432UL);
  ushort* fowb = (ushort*)(ws + 6 * P + 33554432UL + 393216UL);
  float* bufT = out;

  dim3 blk(256);
  dim3 blk1024(1024);

  // weight preconvert + input transpose-splits
  k_wconv<<<dim3(1152), blk, 0, stream>>>(fiw, fow, fiwb, fowb);
  k_tsplit<<<dim3(64, 3, BB), blk, 0, stream>>>(Q,  Qth, Qtl);
  k_tsplit<<<dim3(64, 3, BB), blk, 0, stream>>>(Fn, Fth, Ftl);
  // q stage-1 + dw(+norm partials)
  k_nt3res<<<dim3(128, 3, BB), blk1024, 0, stream>>>(qw1, Qth, Qtl, qb1, bufT, 0);
  k_dw3x3_split<<<dim3(16, CC, BB), blk, 0, stream>>>(bufT, qw2, qb2, qh, ql, pq);
  // merged k+v stage-1; dw-v; dw-k(+partials)
  k_nt3res2<<<dim3(128, 6, BB), blk1024, 0, stream>>>(kw1, vw1, Fth, Ftl,
                                                      kb1, vb1, bufT, vtmp);
  k_dw3x3<<<dim3(16, CC, BB), blk, 0, stream>>>(vtmp, vw2, vb2, vbuf);
  k_dw3x3_split<<<dim3(16, CC, BB), blk, 0, stream>>>(bufT, kw2, kb2, kh, kl, pk);
  // norms (from fused partials) + attention
  k_rnfin<<<dim3(3, 2), blk, 0, stream>>>(pq, pk, rq, rk);
  k_attn_mfma<<<dim3(9, KSPLIT, BB), blk, 0, stream>>>(qh, ql, kh, kl, part);
  k_softmax_topk<<<dim3(CC, BB), dim3(192), 0, stream>>>(part, rq, rk, temp, attnm);
  k_mix<<<dim3(CC, BB), dim3(192), 0, stream>>>(ow, attnm, Mm);
  // Fa = Mm @ v + ob  (reads vbuf fp32 directly)
  k_nt3fa<<<dim3(128, 3, BB), blk1024, 0, stream>>>(Mm, vbuf, ob, Fa);
  // LN -> xnt
  k_ln_t<<<dim3(64, BB), blk, 0, stream>>>(Fa, lnw, lnb, xnt);
  // FFN in 2-batch pairs: fi -> dwglu -> fo
  for (int p = 0; p < 2; ++p) {
    const ushort* xn_p = xnt + (size_t)(2 * p) * NPIX * CC;
    const float*  fa_p = Fa + (size_t)(2 * p) * CC * NPIX;
    float* out_p = out + (size_t)(2 * p) * CC * NPIX;
    k_fi<<<dim3(128, 16, 2), blk, 0, stream>>>(fiwb, xn_p, fib, h2);
    k_dwglu3<<<dim3(64, 64, 2), blk, 0, stream>>>(h2, fdw, fdb, gt2);
    k_fo<<<dim3(128, 3, 2), blk, 0, stream>>>(fowb, gt2, fob, fa_p, out_p);
  }
}

// Round 17
// 610.267 us; speedup vs baseline: 1.0211x; 1.0202x over previous
//
#include <hip/hip_runtime.h>
#include <math.h>
#include <float.h>

#define NPIX 16384
#define CC 192
#define BB 4
#define HHH 128
#define WWW 128
#define HID 510
#define HID2 1020
#define KKEEP 172
#define KSPLIT 16

typedef unsigned short ushort;
typedef unsigned int uint32;
using f32x4  = __attribute__((ext_vector_type(4))) float;
using bf16x8 = __attribute__((ext_vector_type(8))) short;

__device__ __forceinline__ float bf2f(ushort u) {
  union { float f; unsigned int i; } x; x.i = ((unsigned int)u) << 16; return x.f;
}
__device__ __forceinline__ ushort f2bf(float f) {
  union { float f; unsigned int i; } x; x.f = f;
  unsigned int r = (x.i + 0x7FFFu + ((x.i >> 16) & 1u)) >> 16;
  return (ushort)r;
}

struct __align__(16) us8 { ushort u[8]; };
struct __align__(8)  us4 { ushort u[4]; };

// ================= weight preconvert =================
__global__ __launch_bounds__(256) void k_wconv(
    const float* __restrict__ fiw, const float* __restrict__ fow,
    ushort* __restrict__ fiwb, ushort* __restrict__ fowb)
{
  const int idx = blockIdx.x * 256 + threadIdx.x;
  if (idx < 1024 * 192) {
    const int r = idx / 192, c = idx % 192;
    fiwb[idx] = (r < HID2) ? f2bf(fiw[r * 192 + c]) : (ushort)0;
  }
  const int i2 = idx - 1024 * 192;
  if (i2 >= 0 && i2 < 192 * 512) {
    const int r = i2 / 512, c = i2 % 512;
    fowb[i2] = (c < HID) ? f2bf(fow[r * HID + c]) : (ushort)0;
  }
}

// ====== merged transpose+split for Q and Fn: fp32 [C][NPIX] -> [NPIX][192] ===
// grid y in [0,6): y<3 -> Q -> Qt planes; y>=3 -> Fn -> Ft planes.
__global__ __launch_bounds__(256) void k_tsplit2(
    const float* __restrict__ Q, const float* __restrict__ Fn,
    ushort* __restrict__ Qh, ushort* __restrict__ Ql,
    ushort* __restrict__ Fh, ushort* __restrict__ Fl)
{
  __shared__ float ld[64][261];
  const int b = blockIdx.z;
  const bool sel = blockIdx.y >= 3;
  const int c0 = (sel ? (blockIdx.y - 3) : blockIdx.y) * 64;
  const float* X = sel ? Fn : Q;
  ushort* Xh = sel ? Fh : Qh;
  ushort* Xl = sel ? Fl : Ql;
  const int px0 = blockIdx.x * 256;
  const int tid = threadIdx.x;
  #pragma unroll
  for (int i = 0; i < 16; ++i) {
    const int u = i * 256 + tid;
    const int r = u >> 6, p4 = (u & 63) * 4;
    const float4 v = *reinterpret_cast<const float4*>(
        X + ((size_t)b * CC + c0 + r) * NPIX + px0 + p4);
    ld[r][p4] = v.x; ld[r][p4 + 1] = v.y; ld[r][p4 + 2] = v.z; ld[r][p4 + 3] = v.w;
  }
  __syncthreads();
  const int c8 = (tid & 7) * 8;
  #pragma unroll
  for (int it = 0; it < 8; ++it) {
    const int pl = it * 32 + (tid >> 3);
    us8 hi, lo;
    #pragma unroll
    for (int j = 0; j < 8; ++j) {
      const float v = ld[c8 + j][pl];
      const ushort h = f2bf(v);
      hi.u[j] = h; lo.u[j] = f2bf(v - bf2f(h));
    }
    const size_t off = ((size_t)b * NPIX + px0 + pl) * CC + c0 + c8;
    *reinterpret_cast<us8*>(Xh + off) = hi;
    *reinterpret_cast<us8*>(Xl + off) = lo;
  }
}

// ===== resident NT 3-pass GEMM, 16-wave (1024 thr): q stage-1 — R16-verified =
__global__ __launch_bounds__(1024) void k_nt3res(
    const float* __restrict__ W,
    const ushort* __restrict__ Bh, const ushort* __restrict__ Bl,
    const float* __restrict__ bias, float* __restrict__ C,
    long long sAb)
{
  __shared__ ushort As[2][64][200];
  __shared__ ushort Bs[2][128][200];
  const int b = blockIdx.z;
  const int n0 = blockIdx.x * 128;
  const int m0 = blockIdx.y * 64;
  const int tid = threadIdx.x;
  const int lane = tid & 63;
  const int wave = tid >> 6;
  const int wm = wave >> 2, wn = wave & 3;
  const float*  Wb  = W  + (size_t)b * sAb;
  const ushort* Bhb = Bh + (size_t)b * NPIX * CC;
  const ushort* Blb = Bl + (size_t)b * NPIX * CC;

  #pragma unroll
  for (int i = 0; i < 3; ++i) {
    const int u = i * 1024 + tid;
    const int r = u / 48, c = (u % 48) * 4;
    const float4 v = *reinterpret_cast<const float4*>(Wb + (size_t)(m0 + r) * CC + c);
    const float e[4] = {v.x, v.y, v.z, v.w};
    us4 hi, lo;
    #pragma unroll
    for (int t = 0; t < 4; ++t) {
      const ushort h = f2bf(e[t]);
      hi.u[t] = h; lo.u[t] = f2bf(e[t] - bf2f(h));
    }
    *reinterpret_cast<us4*>(&As[0][r][c]) = hi;
    *reinterpret_cast<us4*>(&As[1][r][c]) = lo;
  }
  #pragma unroll
  for (int i = 0; i < 3; ++i) {
    const int u = i * 1024 + tid;
    const int r = u / 24, c = (u % 24) * 8;
    *reinterpret_cast<us8*>(&Bs[0][r][c]) =
        *reinterpret_cast<const us8*>(Bhb + (size_t)(n0 + r) * CC + c);
    *reinterpret_cast<us8*>(&Bs[1][r][c]) =
        *reinterpret_cast<const us8*>(Blb + (size_t)(n0 + r) * CC + c);
  }
  __syncthreads();

  f32x4 acc[2];
  acc[0] = (f32x4){0.f, 0.f, 0.f, 0.f};
  acc[1] = (f32x4){0.f, 0.f, 0.f, 0.f};

  #pragma unroll
  for (int kk = 0; kk < 6; ++kk) {
    bf16x8 af[2], bfg[2][2];
    #pragma unroll
    for (int p = 0; p < 2; ++p)
      af[p] = *reinterpret_cast<const bf16x8*>(
          &As[p][wm * 16 + (lane & 15)][kk * 32 + (lane >> 4) * 8]);
    #pragma unroll
    for (int ni = 0; ni < 2; ++ni)
      #pragma unroll
      for (int p = 0; p < 2; ++p)
        bfg[ni][p] = *reinterpret_cast<const bf16x8*>(
            &Bs[p][wn * 32 + ni * 16 + (lane & 15)][kk * 32 + (lane >> 4) * 8]);
    #pragma unroll
    for (int ni = 0; ni < 2; ++ni) {
      acc[ni] = __builtin_amdgcn_mfma_f32_16x16x32_bf16(af[0], bfg[ni][0], acc[ni], 0, 0, 0);
      acc[ni] = __builtin_amdgcn_mfma_f32_16x16x32_bf16(af[0], bfg[ni][1], acc[ni], 0, 0, 0);
      acc[ni] = __builtin_amdgcn_mfma_f32_16x16x32_bf16(af[1], bfg[ni][0], acc[ni], 0, 0, 0);
    }
  }

  #pragma unroll
  for (int r = 0; r < 4; ++r) {
    const int m = m0 + wm * 16 + (lane >> 4) * 4 + r;
    const float bv = bias[m];
    #pragma unroll
    for (int ni = 0; ni < 2; ++ni) {
      const int n = n0 + wn * 32 + ni * 16 + (lane & 15);
      C[(size_t)b * CC * NPIX + (size_t)m * NPIX + n] = acc[ni][r] + bv;
    }
  }
}

// ====== Fa GEMM, 16-wave: B = fp32 v, transposed+split in staging — R16 ======
__global__ __launch_bounds__(1024) void k_nt3fa(
    const float* __restrict__ W, const float* __restrict__ V,
    const float* __restrict__ bias, float* __restrict__ C)
{
  __shared__ ushort As[2][64][200];
  __shared__ ushort Bs[2][128][200];
  const int b = blockIdx.z;
  const int n0 = blockIdx.x * 128;
  const int m0 = blockIdx.y * 64;
  const int tid = threadIdx.x;
  const int lane = tid & 63;
  const int wave = tid >> 6;
  const int wm = wave >> 2, wn = wave & 3;
  const float* Wb = W + (size_t)b * CC * CC;
  const float* Vb = V + (size_t)b * CC * NPIX;

  #pragma unroll
  for (int i = 0; i < 3; ++i) {
    const int u = i * 1024 + tid;
    const int r = u / 48, c = (u % 48) * 4;
    const float4 v = *reinterpret_cast<const float4*>(Wb + (size_t)(m0 + r) * CC + c);
    const float e[4] = {v.x, v.y, v.z, v.w};
    us4 hi, lo;
    #pragma unroll
    for (int t = 0; t < 4; ++t) {
      const ushort h = f2bf(e[t]);
      hi.u[t] = h; lo.u[t] = f2bf(e[t] - bf2f(h));
    }
    *reinterpret_cast<us4*>(&As[0][r][c]) = hi;
    *reinterpret_cast<us4*>(&As[1][r][c]) = lo;
  }
  {
    const int half = tid >> 9;
    const int krp = (tid & 511) >> 5;
    const int n4 = (tid & 31) * 4;
    #pragma unroll
    for (int i = 0; i < 3; ++i) {
      const int kk0 = half * 96 + i * 32;
      const float4 f0 = *reinterpret_cast<const float4*>(
          Vb + (size_t)(kk0 + 2 * krp) * NPIX + n0 + n4);
      const float4 f1 = *reinterpret_cast<const float4*>(
          Vb + (size_t)(kk0 + 2 * krp + 1) * NPIX + n0 + n4);
      const float e0[4] = {f0.x, f0.y, f0.z, f0.w};
      const float e1[4] = {f1.x, f1.y, f1.z, f1.w};
      #pragma unroll
      for (int j = 0; j < 4; ++j) {
        const ushort h0 = f2bf(e0[j]), h1 = f2bf(e1[j]);
        const ushort l0 = f2bf(e0[j] - bf2f(h0)), l1 = f2bf(e1[j] - bf2f(h1));
        *reinterpret_cast<uint32*>(&Bs[0][n4 + j][kk0 + 2 * krp]) =
            (uint32)h0 | ((uint32)h1 << 16);
        *reinterpret_cast<uint32*>(&Bs[1][n4 + j][kk0 + 2 * krp]) =
            (uint32)l0 | ((uint32)l1 << 16);
      }
    }
  }
  __syncthreads();

  f32x4 acc[2];
  acc[0] = (f32x4){0.f, 0.f, 0.f, 0.f};
  acc[1] = (f32x4){0.f, 0.f, 0.f, 0.f};

  #pragma unroll
  for (int kk = 0; kk < 6; ++kk) {
    bf16x8 af[2], bfg[2][2];
    #pragma unroll
    for (int p = 0; p < 2; ++p)
      af[p] = *reinterpret_cast<const bf16x8*>(
          &As[p][wm * 16 + (lane & 15)][kk * 32 + (lane >> 4) * 8]);
    #pragma unroll
    for (int ni = 0; ni < 2; ++ni)
      #pragma unroll
      for (int p = 0; p < 2; ++p)
        bfg[ni][p] = *reinterpret_cast<const bf16x8*>(
            &Bs[p][wn * 32 + ni * 16 + (lane & 15)][kk * 32 + (lane >> 4) * 8]);
    #pragma unroll
    for (int ni = 0; ni < 2; ++ni) {
      acc[ni] = __builtin_amdgcn_mfma_f32_16x16x32_bf16(af[0], bfg[ni][0], acc[ni], 0, 0, 0);
      acc[ni] = __builtin_amdgcn_mfma_f32_16x16x32_bf16(af[0], bfg[ni][1], acc[ni], 0, 0, 0);
      acc[ni] = __builtin_amdgcn_mfma_f32_16x16x32_bf16(af[1], bfg[ni][0], acc[ni], 0, 0, 0);
    }
  }

  #pragma unroll
  for (int r = 0; r < 4; ++r) {
    const int m = m0 + wm * 16 + (lane >> 4) * 4 + r;
    const float bv = bias[m];
    #pragma unroll
    for (int ni = 0; ni < 2; ++ni) {
      const int n = n0 + wn * 32 + ni * 16 + (lane & 15);
      C[(size_t)b * CC * NPIX + (size_t)m * NPIX + n] = acc[ni][r] + bv;
    }
  }
}

// ================= merged k+v stage-1, 16-wave — R16-verified ================
__global__ __launch_bounds__(1024) void k_nt3res2(
    const float* __restrict__ W1, const float* __restrict__ W2,
    const ushort* __restrict__ Bh, const ushort* __restrict__ Bl,
    const float* __restrict__ b1, const float* __restrict__ b2,
    float* __restrict__ C1, float* __restrict__ C2)
{
  __shared__ ushort As[2][64][200];
  __shared__ ushort Bs[2][128][200];
  const int b = blockIdx.z;
  const int n0 = blockIdx.x * 128;
  const bool sel = blockIdx.y >= 3;
  const int m0 = (sel ? (blockIdx.y - 3) : blockIdx.y) * 64;
  const float* W = sel ? W2 : W1;
  const float* bias = sel ? b2 : b1;
  float* C = sel ? C2 : C1;
  const int tid = threadIdx.x;
  const int lane = tid & 63;
  const int wave = tid >> 6;
  const int wm = wave >> 2, wn = wave & 3;
  const ushort* Bhb = Bh + (size_t)b * NPIX * CC;
  const ushort* Blb = Bl + (size_t)b * NPIX * CC;

  #pragma unroll
  for (int i = 0; i < 3; ++i) {
    const int u = i * 1024 + tid;
    const int r = u / 48, c = (u % 48) * 4;
    const float4 v = *reinterpret_cast<const float4*>(W + (size_t)(m0 + r) * CC + c);
    const float e[4] = {v.x, v.y, v.z, v.w};
    us4 hi, lo;
    #pragma unroll
    for (int t = 0; t < 4; ++t) {
      const ushort h = f2bf(e[t]);
      hi.u[t] = h; lo.u[t] = f2bf(e[t] - bf2f(h));
    }
    *reinterpret_cast<us4*>(&As[0][r][c]) = hi;
    *reinterpret_cast<us4*>(&As[1][r][c]) = lo;
  }
  #pragma unroll
  for (int i = 0; i < 3; ++i) {
    const int u = i * 1024 + tid;
    const int r = u / 24, c = (u % 24) * 8;
    *reinterpret_cast<us8*>(&Bs[0][r][c]) =
        *reinterpret_cast<const us8*>(Bhb + (size_t)(n0 + r) * CC + c);
    *reinterpret_cast<us8*>(&Bs[1][r][c]) =
        *reinterpret_cast<const us8*>(Blb + (size_t)(n0 + r) * CC + c);
  }
  __syncthreads();

  f32x4 acc[2];
  acc[0] = (f32x4){0.f, 0.f, 0.f, 0.f};
  acc[1] = (f32x4){0.f, 0.f, 0.f, 0.f};

  #pragma unroll
  for (int kk = 0; kk < 6; ++kk) {
    bf16x8 af[2], bfg[2][2];
    #pragma unroll
    for (int p = 0; p < 2; ++p)
      af[p] = *reinterpret_cast<const bf16x8*>(
          &As[p][wm * 16 + (lane & 15)][kk * 32 + (lane >> 4) * 8]);
    #pragma unroll
    for (int ni = 0; ni < 2; ++ni)
      #pragma unroll
      for (int p = 0; p < 2; ++p)
        bfg[ni][p] = *reinterpret_cast<const bf16x8*>(
            &Bs[p][wn * 32 + ni * 16 + (lane & 15)][kk * 32 + (lane >> 4) * 8]);
    #pragma unroll
    for (int ni = 0; ni < 2; ++ni) {
      acc[ni] = __builtin_amdgcn_mfma_f32_16x16x32_bf16(af[0], bfg[ni][0], acc[ni], 0, 0, 0);
      acc[ni] = __builtin_amdgcn_mfma_f32_16x16x32_bf16(af[0], bfg[ni][1], acc[ni], 0, 0, 0);
      acc[ni] = __builtin_amdgcn_mfma_f32_16x16x32_bf16(af[1], bfg[ni][0], acc[ni], 0, 0, 0);
    }
  }

  #pragma unroll
  for (int r = 0; r < 4; ++r) {
    const int m = m0 + wm * 16 + (lane >> 4) * 4 + r;
    const float bv = bias[m];
    #pragma unroll
    for (int ni = 0; ni < 2; ++ni) {
      const int n = n0 + wn * 32 + ni * 16 + (lane & 15);
      C[(size_t)b * CC * NPIX + (size_t)m * NPIX + n] = acc[ni][r] + bv;
    }
  }
}

// ================= fi GEMM v2: 64m x 128n, 76.8 KB LDS — R11-verified ========
__global__ __launch_bounds__(256) void k_fi(
    const ushort* __restrict__ Aw, const ushort* __restrict__ Bt,
    const float* __restrict__ bias, ushort* __restrict__ H)
{
  __shared__ ushort lds[64 * 200 + 128 * 200];
  ushort (*As)[200] = reinterpret_cast<ushort(*)[200]>(lds);
  ushort (*Bs)[200] = reinterpret_cast<ushort(*)[200]>(lds + 64 * 200);
  ushort (*Cs)[132] = reinterpret_cast<ushort(*)[132]>(lds);
  const int z = blockIdx.z;
  const int n0 = blockIdx.x * 128;
  const int m0 = blockIdx.y * 64;
  const int tid = threadIdx.x;
  const int lane = tid & 63;
  const int wave = tid >> 6;
  const int wm = wave >> 1, wn = wave & 1;
  const ushort* Bb = Bt + (size_t)z * NPIX * CC;
  ushort* Hb = H + (size_t)z * 1024 * NPIX;

  #pragma unroll
  for (int i = 0; i < 6; ++i) {
    const int u = i * 256 + tid;
    const int r = u / 24, c = (u % 24) * 8;
    *reinterpret_cast<us8*>(&As[r][c]) =
        *reinterpret_cast<const us8*>(Aw + (size_t)(m0 + r) * CC + c);
  }
  #pragma unroll
  for (int i = 0; i < 12; ++i) {
    const int u = i * 256 + tid;
    const int r = u / 24, c = (u % 24) * 8;
    *reinterpret_cast<us8*>(&Bs[r][c]) =
        *reinterpret_cast<const us8*>(Bb + (size_t)(n0 + r) * CC + c);
  }
  __syncthreads();

  f32x4 acc[2][4];
  #pragma unroll
  for (int i = 0; i < 2; ++i)
    #pragma unroll
    for (int j = 0; j < 4; ++j) acc[i][j] = (f32x4){0.f, 0.f, 0.f, 0.f};

  #pragma unroll
  for (int kk = 0; kk < 6; ++kk) {
    bf16x8 af[2], bfg[4];
    #pragma unroll
    for (int mi = 0; mi < 2; ++mi)
      af[mi] = *reinterpret_cast<const bf16x8*>(
          &As[wm * 32 + mi * 16 + (lane & 15)][kk * 32 + (lane >> 4) * 8]);
    #pragma unroll
    for (int ni = 0; ni < 4; ++ni)
      bfg[ni] = *reinterpret_cast<const bf16x8*>(
          &Bs[wn * 64 + ni * 16 + (lane & 15)][kk * 32 + (lane >> 4) * 8]);
    #pragma unroll
    for (int mi = 0; mi < 2; ++mi)
      #pragma unroll
      for (int ni = 0; ni < 4; ++ni)
        acc[mi][ni] = __builtin_amdgcn_mfma_f32_16x16x32_bf16(
            af[mi], bfg[ni], acc[mi][ni], 0, 0, 0);
  }

  __syncthreads();
  #pragma unroll
  for (int mi = 0; mi < 2; ++mi)
    #pragma unroll
    for (int rr = 0; rr < 4; ++rr) {
      const int rloc = wm * 32 + mi * 16 + (lane >> 4) * 4 + rr;
      const int m = m0 + rloc;
      const float bv = (m < HID2) ? bias[m] : 0.f;
      #pragma unroll
      for (int ni = 0; ni < 4; ++ni) {
        const int cc = wn * 64 + ni * 16 + (lane & 15);
        Cs[rloc][cc] = f2bf(acc[mi][ni][rr] + bv);
      }
    }
  __syncthreads();
  #pragma unroll
  for (int it = 0; it < 4; ++it) {
    const int r = it * 16 + (tid >> 4);
    const int c8 = (tid & 15) * 8;
    *reinterpret_cast<us8*>(Hb + (size_t)(m0 + r) * NPIX + n0 + c8) =
        *reinterpret_cast<const us8*>(&Cs[r][c8]);
  }
}

// ================= fo GEMM: A resident, B double-buffered — R11-verified =====
__global__ __launch_bounds__(256) void k_fo(
    const ushort* __restrict__ Aw, const ushort* __restrict__ Bt,
    const float* __restrict__ bias, const float* __restrict__ res,
    float* __restrict__ C)
{
  __shared__ ushort As[64][520];
  __shared__ ushort Bs[2][128][136];
  const int z = blockIdx.z;
  const int n0 = blockIdx.x * 128;
  const int m0 = blockIdx.y * 64;
  const int tid = threadIdx.x;
  const int lane = tid & 63;
  const int wave = tid >> 6;
  const int wm = wave >> 1, wn = wave & 1;
  const ushort* Bb = Bt + (size_t)z * NPIX * 512;
  const float* resb = res + (size_t)z * CC * NPIX;
  float* Cb = C + (size_t)z * CC * NPIX;

  #pragma unroll
  for (int i = 0; i < 16; ++i) {
    const int u = i * 256 + tid;
    const int r = u >> 6, c = (u & 63) * 8;
    *reinterpret_cast<us8*>(&As[r][c]) =
        *reinterpret_cast<const us8*>(Aw + (size_t)(m0 + r) * 512 + c);
  }
  #pragma unroll
  for (int i = 0; i < 8; ++i) {
    const int u = i * 256 + tid;
    const int r = u >> 4, c = (u & 15) * 8;
    *reinterpret_cast<us8*>(&Bs[0][r][c]) =
        *reinterpret_cast<const us8*>(Bb + (size_t)(n0 + r) * 512 + c);
  }
  __syncthreads();

  f32x4 acc[2][4];
  #pragma unroll
  for (int i = 0; i < 2; ++i)
    #pragma unroll
    for (int j = 0; j < 4; ++j) acc[i][j] = (f32x4){0.f, 0.f, 0.f, 0.f};

  for (int t = 0; t < 4; ++t) {
    us8 rg[8];
    if (t < 3) {
      #pragma unroll
      for (int i = 0; i < 8; ++i) {
        const int u = i * 256 + tid;
        const int r = u >> 4, c = (u & 15) * 8;
        rg[i] = *reinterpret_cast<const us8*>(
            Bb + (size_t)(n0 + r) * 512 + (t + 1) * 128 + c);
      }
    }
    const int cur = t & 1;
    #pragma unroll
    for (int ks = 0; ks < 4; ++ks) {
      bf16x8 af[2], bfg[4];
      #pragma unroll
      for (int mi = 0; mi < 2; ++mi)
        af[mi] = *reinterpret_cast<const bf16x8*>(
            &As[wm * 32 + mi * 16 + (lane & 15)][t * 128 + ks * 32 + (lane >> 4) * 8]);
      #pragma unroll
      for (int ni = 0; ni < 4; ++ni)
        bfg[ni] = *reinterpret_cast<const bf16x8*>(
            &Bs[cur][wn * 64 + ni * 16 + (lane & 15)][ks * 32 + (lane >> 4) * 8]);
      #pragma unroll
      for (int mi = 0; mi < 2; ++mi)
        #pragma unroll
        for (int ni = 0; ni < 4; ++ni)
          acc[mi][ni] = __builtin_amdgcn_mfma_f32_16x16x32_bf16(
              af[mi], bfg[ni], acc[mi][ni], 0, 0, 0);
    }
    if (t < 3) {
      #pragma unroll
      for (int i = 0; i < 8; ++i) {
        const int u = i * 256 + tid;
        const int r = u >> 4, c = (u & 15) * 8;
        *reinterpret_cast<us8*>(&Bs[cur ^ 1][r][c]) = rg[i];
      }
    }
    __syncthreads();
  }

  #pragma unroll
  for (int mi = 0; mi < 2; ++mi)
    #pragma unroll
    for (int r = 0; r < 4; ++r) {
      const int m = m0 + wm * 32 + mi * 16 + (lane >> 4) * 4 + r;
      const float bv = bias[m];
      #pragma unroll
      for (int ni = 0; ni < 4; ++ni) {
        const int n = n0 + wn * 64 + ni * 16 + (lane & 15);
        Cb[(size_t)m * NPIX + n] = acc[mi][ni][r] + bv + resb[(size_t)m * NPIX + n];
      }
    }
}

// ================= attn logits: MFMA 3-pass split-K — verified ===============
__global__ __launch_bounds__(256) void k_attn_mfma(
    const ushort* __restrict__ qh, const ushort* __restrict__ ql,
    const ushort* __restrict__ kh, const ushort* __restrict__ kl,
    float* __restrict__ part)
{
  __shared__ ushort As[2][64][40];
  __shared__ ushort Bs[2][64][40];
  const int b = blockIdx.z;
  const int tr = blockIdx.x / 3, tc = blockIdx.x % 3;
  const int r0 = tr * 64, c0 = tc * 64;
  const int k0 = blockIdx.y * (NPIX / KSPLIT);
  const int tid = threadIdx.x;
  const int lane = tid & 63;
  const int wave = tid >> 6;
  const int wm = wave >> 1, wn = wave & 1;

  f32x4 acc[2][2];
  #pragma unroll
  for (int i = 0; i < 2; ++i)
    #pragma unroll
    for (int j = 0; j < 2; ++j) acc[i][j] = (f32x4){0.f, 0.f, 0.f, 0.f};

  const int ar = tid >> 2, ak = (tid & 3) * 8;

  for (int kc = 0; kc < NPIX / KSPLIT; kc += 32) {
    const size_t qo = (size_t)(b * CC + r0 + ar) * NPIX + k0 + kc + ak;
    const size_t ko = (size_t)(b * CC + c0 + ar) * NPIX + k0 + kc + ak;
    *reinterpret_cast<us8*>(&As[0][ar][ak]) = *reinterpret_cast<const us8*>(qh + qo);
    *reinterpret_cast<us8*>(&As[1][ar][ak]) = *reinterpret_cast<const us8*>(ql + qo);
    *reinterpret_cast<us8*>(&Bs[0][ar][ak]) = *reinterpret_cast<const us8*>(kh + ko);
    *reinterpret_cast<us8*>(&Bs[1][ar][ak]) = *reinterpret_cast<const us8*>(kl + ko);
    __syncthreads();
    bf16x8 af[2][2], bfr[2][2];
    #pragma unroll
    for (int mi = 0; mi < 2; ++mi)
      #pragma unroll
      for (int p = 0; p < 2; ++p)
        af[mi][p] = *reinterpret_cast<const bf16x8*>(
            &As[p][wm * 32 + mi * 16 + (lane & 15)][(lane >> 4) * 8]);
    #pragma unroll
    for (int ni = 0; ni < 2; ++ni)
      #pragma unroll
      for (int p = 0; p < 2; ++p)
        bfr[ni][p] = *reinterpret_cast<const bf16x8*>(
            &Bs[p][wn * 32 + ni * 16 + (lane & 15)][(lane >> 4) * 8]);
    #pragma unroll
    for (int mi = 0; mi < 2; ++mi)
      #pragma unroll
      for (int ni = 0; ni < 2; ++ni) {
        acc[mi][ni] = __builtin_amdgcn_mfma_f32_16x16x32_bf16(
            af[mi][0], bfr[ni][0], acc[mi][ni], 0, 0, 0);
        acc[mi][ni] = __builtin_amdgcn_mfma_f32_16x16x32_bf16(
            af[mi][0], bfr[ni][1], acc[mi][ni], 0, 0, 0);
        acc[mi][ni] = __builtin_amdgcn_mfma_f32_16x16x32_bf16(
            af[mi][1], bfr[ni][0], acc[mi][ni], 0, 0, 0);
      }
    __syncthreads();
  }

  float* pp = part + (size_t)(blockIdx.y * BB + b) * CC * CC;
  #pragma unroll
  for (int mi = 0; mi < 2; ++mi)
    #pragma unroll
    for (int r = 0; r < 4; ++r) {
      const int row = r0 + wm * 32 + mi * 16 + (lane >> 4) * 4 + r;
      #pragma unroll
      for (int ni = 0; ni < 2; ++ni) {
        const int col = c0 + wn * 32 + ni * 16 + (lane & 15);
        pp[(size_t)row * CC + col] = acc[mi][ni][r];
      }
    }
}

// ================= depthwise 3x3 helper =================
__device__ __forceinline__ void dw4(const float* __restrict__ Xc,
                                    const float* __restrict__ wt, float bv,
                                    int h, int w, float out[4])
{
  float a0, a1, a2, a3;
  a0 = a1 = a2 = a3 = bv;
  #pragma unroll
  for (int dy = 0; dy < 3; ++dy) {
    const int hh = h + dy - 1;
    if (hh < 0 || hh >= HHH) continue;
    const float* row = Xc + hh * WWW + w;
    const float xm = (w > 0) ? row[-1] : 0.f;
    const float4 xc = *reinterpret_cast<const float4*>(row);
    const float xp = (w < WWW - 4) ? row[4] : 0.f;
    const float w0 = wt[dy * 3 + 0], w1 = wt[dy * 3 + 1], w2 = wt[dy * 3 + 2];
    a0 += w0 * xm   + w1 * xc.x + w2 * xc.y;
    a1 += w0 * xc.x + w1 * xc.y + w2 * xc.z;
    a2 += w0 * xc.y + w1 * xc.z + w2 * xc.w;
    a3 += w0 * xc.z + w1 * xc.w + w2 * xp;
  }
  out[0] = a0; out[1] = a1; out[2] = a2; out[3] = a3;
}

// plain dw3x3 (v path) — R11-verified
__global__ __launch_bounds__(256) void k_dw3x3(
    const float* __restrict__ X, const float* __restrict__ W9,
    const float* __restrict__ bias, float* __restrict__ Y)
{
  const int b = blockIdx.z, c = blockIdx.y;
  const int p = blockIdx.x * 1024 + threadIdx.x * 4;
  const int h = p >> 7, w = p & 127;
  float o[4];
  dw4(X + (size_t)(b * CC + c) * NPIX, W9 + c * 9, bias[c], h, w, o);
  *reinterpret_cast<float4*>(Y + (size_t)(b * CC + c) * NPIX + p) =
      make_float4(o[0], o[1], o[2], o[3]);
}

// dw3x3 + hi/lo split planes [c][px] + row-norm partials (fused) — verified
__global__ __launch_bounds__(256) void k_dw3x3_split(
    const float* __restrict__ X, const float* __restrict__ W9,
    const float* __restrict__ bias, ushort* __restrict__ Yh,
    ushort* __restrict__ Yl, float* __restrict__ partial)
{
  const int b = blockIdx.z, c = blockIdx.y;
  const int p = blockIdx.x * 1024 + threadIdx.x * 4;
  const int h = p >> 7, w = p & 127;
  float o[4];
  dw4(X + (size_t)(b * CC + c) * NPIX, W9 + c * 9, bias[c], h, w, o);
  us4 hi, lo;
  #pragma unroll
  for (int t = 0; t < 4; ++t) {
    const ushort hv = f2bf(o[t]);
    hi.u[t] = hv;
    lo.u[t] = f2bf(o[t] - bf2f(hv));
  }
  const size_t off = (size_t)(b * CC + c) * NPIX + p;
  *reinterpret_cast<us4*>(Yh + off) = hi;
  *reinterpret_cast<us4*>(Yl + off) = lo;
  __shared__ float sm[256];
  sm[threadIdx.x] = o[0]*o[0] + o[1]*o[1] + o[2]*o[2] + o[3]*o[3];
  __syncthreads();
  for (int st = 128; st > 0; st >>= 1) {
    if (threadIdx.x < st) sm[threadIdx.x] += sm[threadIdx.x + st];
    __syncthreads();
  }
  if (threadIdx.x == 0)
    partial[(size_t)(b * CC + c) * 16 + blockIdx.x] = sm[0];
}

// ================= softmax + topk mask (norms computed inline) ===============
__global__ __launch_bounds__(192) void k_softmax_topk(
    const float* __restrict__ part, const float* __restrict__ pq,
    const float* __restrict__ pk, const float* __restrict__ temp,
    float* __restrict__ attnm)
{
  const int c = blockIdx.x, b = blockIdx.y, d = threadIdx.x;
  // inline reciprocal norms (fixed ascending order — identical to k_rnfin)
  float sq = 0.f, sk = 0.f;
  #pragma unroll
  for (int i = 0; i < 16; ++i) {
    sq += pq[(size_t)(b * CC + c) * 16 + i];
    sk += pk[(size_t)(b * CC + d) * 16 + i];
  }
  const float rqv = 1.f / fmaxf(sqrtf(sq), 1e-12f);
  const float rkv = 1.f / fmaxf(sqrtf(sk), 1e-12f);
  float s = 0.f;
  for (int ksp = 0; ksp < KSPLIT; ++ksp)
    s += part[(size_t)(ksp * BB + b) * CC * CC + c * CC + d];
  const float logit = s * rqv * rkv * temp[0];
  __shared__ float sa[CC], sb[CC];
  sa[d] = logit; __syncthreads();
  float mx = -FLT_MAX;
  for (int j = 0; j < CC; ++j) mx = fmaxf(mx, sa[j]);
  const float e = expf(logit - mx);
  sb[d] = e; __syncthreads();
  float sum = 0.f;
  for (int j = 0; j < CC; ++j) sum += sb[j];
  const float pv = e / sum;
  __syncthreads();
  sa[d] = pv; __syncthreads();
  int greater = 0;
  for (int j = 0; j < CC; ++j) greater += (sa[j] > pv) ? 1 : 0;
  const float cand = (greater < KKEEP) ? pv : FLT_MAX;
  sb[d] = cand; __syncthreads();
  float thr = FLT_MAX;
  for (int j = 0; j < CC; ++j) thr = fminf(thr, sb[j]);
  attnm[(size_t)(b * CC + c) * CC + d] = (pv >= thr) ? pv : 0.f;
}

// ================= M[b] = ow @ attnm[b] =================
__global__ __launch_bounds__(192) void k_mix(
    const float* __restrict__ ow, const float* __restrict__ attnm,
    float* __restrict__ M)
{
  const int c = blockIdx.x, b = blockIdx.y, d = threadIdx.x;
  float acc = 0.f;
  for (int e = 0; e < CC; ++e)
    acc += ow[c * CC + e] * attnm[(size_t)(b * CC + e) * CC + d];
  M[(size_t)(b * CC + c) * CC + d] = acc;
}

// ================= LayerNorm -> transposed bf16 [px][192] =================
__global__ __launch_bounds__(256) void k_ln_t(
    const float* __restrict__ X, const float* __restrict__ lw,
    const float* __restrict__ lb, ushort* __restrict__ Y)
{
  const int b = blockIdx.y;
  const int n = blockIdx.x * 256 + threadIdx.x;
  const float* Xb = X + (size_t)b * CC * NPIX + n;
  float s = 0.f, s2 = 0.f;
  for (int ci = 0; ci < CC; ++ci) {
    const float v = Xb[(size_t)ci * NPIX];
    s += v; s2 += v * v;
  }
  const float mu = s * (1.f / CC);
  const float var = fmaxf(s2 * (1.f / CC) - mu * mu, 0.f);
  const float rstd = rsqrtf(var + 1e-5f);
  ushort* Yb = Y + ((size_t)b * NPIX + n) * CC;
  for (int c8 = 0; c8 < CC / 8; ++c8) {
    bf16x8 sv;
    #pragma unroll
    for (int t = 0; t < 8; ++t) {
      const int c = c8 * 8 + t;
      const float v = Xb[(size_t)c * NPIX];
      sv[t] = (short)f2bf((v - mu) * rstd * lw[c] + lb[c]);
    }
    *reinterpret_cast<bf16x8*>(Yb + c8 * 8) = sv;
  }
}

// ================= fused depthwise 3x3 + GLU v3 — verified R8 ================
__device__ __forceinline__ float gelu_exact(float x) {
  return 0.5f * x * (1.f + erff(x * 0.70710678118654752f));
}

__global__ __launch_bounds__(256) void k_dwglu3(
    const ushort* __restrict__ Hp, const float* __restrict__ fdw,
    const float* __restrict__ fdb, ushort* __restrict__ gt)
{
  __shared__ ushort hs[16][4][128];
  __shared__ uint32 gsd[8 * 129];
  const int z = blockIdx.z;
  const int c0 = blockIdx.x * 8;
  const int h0 = blockIdx.y * 2;
  const int tid = threadIdx.x;
  const int npairs = min(8, HID - c0);
  const ushort* Hb = Hp + (size_t)z * 1024 * NPIX;

  #pragma unroll
  for (int i = 0; i < 4; ++i) {
    const int u = i * 256 + tid;
    const int ch = u >> 6;
    const int row = (u >> 4) & 3;
    const int w0 = (u & 15) * 8;
    const int grow = h0 - 1 + row;
    const int cloc = ch & 7;
    const int gch = (ch < 8) ? (c0 + cloc) : (HID + c0 + cloc);
    us8 v;
    #pragma unroll
    for (int t = 0; t < 8; ++t) v.u[t] = 0;
    if (c0 + cloc < HID && grow >= 0 && grow < HHH)
      v = *reinterpret_cast<const us8*>(Hb + (size_t)gch * NPIX + grow * WWW + w0);
    *reinterpret_cast<us8*>(&hs[ch][row][w0]) = v;
  }
  __syncthreads();

  const int q = tid & 63;
  const int jp = tid >> 6;
  const int px_l = q * 4;
  const int dh = px_l >> 7;
  const int w = px_l & 127;

  #pragma unroll
  for (int jj = 0; jj < 2; ++jj) {
    const int j = jp * 2 + jj;
    uint32 p0 = 0, p1 = 0;
    if (j < npairs) {
      const float* w1 = fdw + (size_t)(c0 + j) * 9;
      const float* w2 = fdw + (size_t)(HID + c0 + j) * 9;
      float x1[4], x2[4];
      const float b1 = fdb[c0 + j], b2 = fdb[HID + c0 + j];
      #pragma unroll
      for (int i = 0; i < 4; ++i) { x1[i] = b1; x2[i] = b2; }
      #pragma unroll
      for (int dy = 0; dy < 3; ++dy) {
        const int row = dh + dy;
        const ushort* r1 = &hs[j][row][0];
        const ushort* r2 = &hs[8 + j][row][0];
        const float am1 = (w > 0) ? bf2f(r1[w - 1]) : 0.f;
        const float am2 = (w > 0) ? bf2f(r2[w - 1]) : 0.f;
        const us4 c1 = *reinterpret_cast<const us4*>(&r1[w]);
        const us4 c2 = *reinterpret_cast<const us4*>(&r2[w]);
        const float ap1 = (w < 124) ? bf2f(r1[w + 4]) : 0.f;
        const float ap2 = (w < 124) ? bf2f(r2[w + 4]) : 0.f;
        const float e10 = bf2f(c1.u[0]), e11 = bf2f(c1.u[1]);
        const float e12 = bf2f(c1.u[2]), e13 = bf2f(c1.u[3]);
        const float e20 = bf2f(c2.u[0]), e21 = bf2f(c2.u[1]);
        const float e22 = bf2f(c2.u[2]), e23 = bf2f(c2.u[3]);
        const float wa0 = w1[dy * 3 + 0], wa1 = w1[dy * 3 + 1], wa2 = w1[dy * 3 + 2];
        const float wb0 = w2[dy * 3 + 0], wb1 = w2[dy * 3 + 1], wb2 = w2[dy * 3 + 2];
        x1[0] += wa0 * am1 + wa1 * e10 + wa2 * e11;
        x1[1] += wa0 * e10 + wa1 * e11 + wa2 * e12;
        x1[2] += wa0 * e11 + wa1 * e12 + wa2 * e13;
        x1[3] += wa0 * e12 + wa1 * e13 + wa2 * ap1;
        x2[0] += wb0 * am2 + wb1 * e20 + wb2 * e21;
        x2[1] += wb0 * e20 + wb1 * e21 + wb2 * e22;
        x2[2] += wb0 * e21 + wb1 * e22 + wb2 * e23;
        x2[3] += wb0 * e22 + wb1 * e23 + wb2 * ap2;
      }
      const ushort v0 = f2bf(x1[0] * gelu_exact(x2[0]));
      const ushort v1 = f2bf(x1[1] * gelu_exact(x2[1]));
      const ushort v2 = f2bf(x1[2] * gelu_exact(x2[2]));
      const ushort v3 = f2bf(x1[3] * gelu_exact(x2[3]));
      p0 = (uint32)v0 | ((uint32)v1 << 16);
      p1 = (uint32)v2 | ((uint32)v3 << 16);
    }
    gsd[j * 129 + (px_l >> 1)] = p0;
    gsd[j * 129 + (px_l >> 1) + 1] = p1;
  }
  __syncthreads();

  const ushort* gsu = (const ushort*)gsd;
  const int px_l2 = tid;
  const int px = (h0 + (px_l2 >> 7)) * WWW + (px_l2 & 127);
  us8 v;
  #pragma unroll
  for (int t = 0; t < 8; ++t) v.u[t] = gsu[t * 258 + px_l2];
  *reinterpret_cast<us8*>(gt + ((size_t)z * NPIX + px) * 512 + c0) = v;
}

// ================= launch =================
// Workspace layout identical to R15/R16 (peak 185.1 MB, verified).
extern "C" void kernel_launch(void* const* d_in, const int* in_sizes, int n_in,
                              void* d_out, int out_size, void* d_ws, size_t ws_size,
                              hipStream_t stream)
{
  const float* Q    = (const float*)d_in[0];
  const float* Fn   = (const float*)d_in[1];
  const float* temp = (const float*)d_in[2];
  const float* qw1  = (const float*)d_in[3];
  const float* qb1  = (const float*)d_in[4];
  const float* qw2  = (const float*)d_in[5];
  const float* qb2  = (const float*)d_in[6];
  const float* kw1  = (const float*)d_in[7];
  const float* kb1  = (const float*)d_in[8];
  const float* kw2  = (const float*)d_in[9];
  const float* kb2  = (const float*)d_in[10];
  const float* vw1  = (const float*)d_in[11];
  const float* vb1  = (const float*)d_in[12];
  const float* vw2  = (const float*)d_in[13];
  const float* vb2  = (const float*)d_in[14];
  const float* ow   = (const float*)d_in[15];
  const float* ob   = (const float*)d_in[16];
  const float* lnw  = (const float*)d_in[17];
  const float* lnb  = (const float*)d_in[18];
  const float* fiw  = (const float*)d_in[19];
  const float* fib  = (const float*)d_in[20];
  const float* fdw  = (const float*)d_in[21];
  const float* fdb  = (const float*)d_in[22];
  const float* fow  = (const float*)d_in[23];
  const float* fob  = (const float*)d_in[24];
  float* out = (float*)d_out;

  char* ws = (char*)d_ws;
  const size_t P = 25165824UL;
  ushort* Qth = (ushort*)(ws + 0 * P);
  ushort* Qtl = (ushort*)(ws + 1 * P);
  ushort* Fth = (ushort*)(ws + 2 * P);
  ushort* Ftl = (ushort*)(ws + 3 * P);
  ushort* qh  = (ushort*)(ws + 4 * P);
  ushort* ql  = (ushort*)(ws + 5 * P);
  float*  vtmp = (float*)(ws + 0 * P);   // v stage-1 out (over Qt)
  float*  vbuf = (float*)(ws + 2 * P);   // v after dw (over Fnt), read by k_nt3fa
  ushort* kh  = (ushort*)(ws + 0 * P);   // written after dw-v
  ushort* kl  = (ushort*)(ws + 1 * P);
  char* smb = ws + 6 * P;
  float* part  = (float*)(smb + 8192);
  float* attnm = (float*)(smb + 8192 + 9437184);
  float* Mm    = (float*)(smb + 8192 + 9437184 + 589824);
  float* pq    = (float*)(smb + 8192 + 9437184 + 2 * 589824);
  float* pk    = (float*)(smb + 8192 + 9437184 + 2 * 589824 + 49152);
  float*  Fa   = (float*)(ws + 4 * P);
  ushort* xnt  = (ushort*)(ws + 0 * P);
  ushort* h2   = (ushort*)(ws + 1 * P);
  ushort* gt2  = (ushort*)(ws + 6 * P);
  ushort* fiwb = (ushort*)(ws + 6 * P + 33554432UL);
  ushort* fowb = (ushort*)(ws + 6 * P + 33554432UL + 393216UL);
  float* bufT = out;

  dim3 blk(256);
  dim3 blk1024(1024);

  // weight preconvert + merged input transpose-splits (Q and Fn in one launch)
  k_wconv<<<dim3(1152), blk, 0, stream>>>(fiw, fow, fiwb, fowb);
  k_tsplit2<<<dim3(64, 6, BB), blk, 0, stream>>>(Q, Fn, Qth, Qtl, Fth, Ftl);
  // q stage-1 + dw(+norm partials)
  k_nt3res<<<dim3(128, 3, BB), blk1024, 0, stream>>>(qw1, Qth, Qtl, qb1, bufT, 0);
  k_dw3x3_split<<<dim3(16, CC, BB), blk, 0, stream>>>(bufT, qw2, qb2, qh, ql, pq);
  // merged k+v stage-1; dw-v; dw-k(+partials)
  k_nt3res2<<<dim3(128, 6, BB), blk1024, 0, stream>>>(kw1, vw1, Fth, Ftl,
                                                      kb1, vb1, bufT, vtmp);
  k_dw3x3<<<dim3(16, CC, BB), blk, 0, stream>>>(vtmp, vw2, vb2, vbuf);
  k_dw3x3_split<<<dim3(16, CC, BB), blk, 0, stream>>>(bufT, kw2, kb2, kh, kl, pk);
  // attention (norms computed inline in softmax from partials)
  k_attn_mfma<<<dim3(9, KSPLIT, BB), blk, 0, stream>>>(qh, ql, kh, kl, part);
  k_softmax_topk<<<dim3(CC, BB), dim3(192), 0, stream>>>(part, pq, pk, temp, attnm);
  k_mix<<<dim3(CC, BB), dim3(192), 0, stream>>>(ow, attnm, Mm);
  // Fa = Mm @ v + ob  (reads vbuf fp32 directly)
  k_nt3fa<<<dim3(128, 3, BB), blk1024, 0, stream>>>(Mm, vbuf, ob, Fa);
  // LN -> xnt
  k_ln_t<<<dim3(64, BB), blk, 0, stream>>>(Fa, lnw, lnb, xnt);
  // FFN in 2-batch pairs: fi -> dwglu -> fo
  for (int p = 0; p < 2; ++p) {
    const ushort* xn_p = xnt + (size_t)(2 * p) * NPIX * CC;
    const float*  fa_p = Fa + (size_t)(2 * p) * CC * NPIX;
    float* out_p = out + (size_t)(2 * p) * CC * NPIX;
    k_fi<<<dim3(128, 16, 2), blk, 0, stream>>>(fiwb, xn_p, fib, h2);
    k_dwglu3<<<dim3(64, 64, 2), blk, 0, stream>>>(h2, fdw, fdb, gt2);
    k_fo<<<dim3(128, 3, 2), blk, 0, stream>>>(fowb, gt2, fob, fa_p, out_p);
  }
}